// Round 8
// baseline (5265.012 us; speedup 1.0000x reference)
//
#include <hip/hip_runtime.h>

typedef __attribute__((ext_vector_type(8))) short short8;
typedef __attribute__((ext_vector_type(4))) float f32x4;
typedef unsigned short u16;
typedef unsigned int u32;
typedef unsigned long long u64;

// Shapes: B=16, T_ENC=256, T_DEC=64, N_MEL=80, ENC=512, ARNN=DRNN=1024,
// PRENET=256, ATTN_DIM=128, LOC_F=32, LOC_K=31
// attn LSTM K = 1792 (56 tiles of 32); dec K = 2560 (80 tiles)
// MFMA 16x16x32 bf16; C/D: col=lane&15, row=(lane>>4)*4+reg  [HW-verified]
//
// Coherence: cross-block WRITES agent-scope (visible at LLC). Cross-block
// READS are nontemporal loads (coalesced, no L2 allocation) of step-versioned
// addresses that are written-once-before-first-read (virgin lines can't be
// stale; across replays stale == fresh by determinism). UC only for barrier.
//
// launch_bounds(512,1): grid is 1 block/CU; 2 waves/SIMD -> 256-VGPR budget so
// afA[14]+afD[20] (136 VGPRs) stay register-resident WITHOUT scratch spills.
// (512,2) capped at 128 VGPRs and spilled the weight arrays every step (r7).

// ---------------- workspace byte offsets ----------------
static constexpr size_t OFF_WFA   = 0;                 // 14,680,064
static constexpr size_t OFF_WFD   = 14680064;          // +20,971,520 = 35,651,584
static constexpr size_t OFF_PREF  = 35651584;          // +524,288
static constexpr size_t OFF_QWB   = 36175872;          // +262,144
static constexpr size_t OFF_MWT   = 36438016;          // +262,144
static constexpr size_t OFF_BA    = 36700160;          // +16,384
static constexpr size_t OFF_BD    = 36716544;          // +16,384
static constexpr size_t OFF_PM    = 36732928;          // +2,097,152  pm[b][tt][d] f32
static constexpr size_t OFF_CTXF  = 38830080;          // +2,129,920  65 slots f32
static constexpr size_t OFF_DHF   = 40960000;          // +4,259,840  65 slots f32
static constexpr size_t OFF_AHFD  = 45219840;          // +2,129,920  65 x 32KB frag
static constexpr size_t OFF_CTXFD = 47349760;          // +1,064,960  65 x 16KB frag
static constexpr size_t OFF_DHFD  = 48414720;          // +2,129,920  65 x 32KB frag
static constexpr size_t OFF_BAR   = 50544640;          // 256 arrival + 256 flag @64B
static constexpr size_t OFF_END   = 50577408;

__device__ __forceinline__ float sigmf(float x) { return 1.f / (1.f + expf(-x)); }
__device__ __forceinline__ float tanh_fast(float x) {
  float e2 = __expf(2.f * x);
  return 1.f - 2.f / (e2 + 1.f);
}
__device__ __forceinline__ u16 f2bf(float f) {
  u32 u = __float_as_uint(f);
  return (u16)((u + 0x7FFFu + ((u >> 16) & 1u)) >> 16);
}
__device__ __forceinline__ float bf2f(u16 x) { return __uint_as_float(((u32)x) << 16); }

// nontemporal coalesced fragment load (no cache allocation; served from LLC)
__device__ __forceinline__ short8 ld_frag_nt(const void* p) {
  const u64* q = (const u64*)p;
  u64 lo = __builtin_nontemporal_load(q);
  u64 hi = __builtin_nontemporal_load(q + 1);
  union { u64 q2[2]; short8 s; } u;
  u.q2[0] = lo; u.q2[1] = hi;
  return u.s;
}

// agent-scope write helpers (land in LLC)
__device__ __forceinline__ void st_u16_agent(u16* p, u16 v) {
  __hip_atomic_store(p, v, __ATOMIC_RELAXED, __HIP_MEMORY_SCOPE_AGENT);
}
__device__ __forceinline__ void st_f32_agent(float* p, float v) {
  __hip_atomic_store(p, v, __ATOMIC_RELAXED, __HIP_MEMORY_SCOPE_AGENT);
}
__device__ __forceinline__ u32 ld_u32_agent(const u32* p) {
  return __hip_atomic_load(p, __ATOMIC_RELAXED, __HIP_MEMORY_SCOPE_AGENT);
}
__device__ __forceinline__ void st_u32_agent(u32* p, u32 v) {
  __hip_atomic_store(p, v, __ATOMIC_RELAXED, __HIP_MEMORY_SCOPE_AGENT);
}

// Contention-free master/broadcast barrier (private lines, no RMW).
__device__ __forceinline__ void gbar(u32* barr, u32* flg, int bk, int th,
                                     u32 epoch, int master) {
  __syncthreads();   // drains vmcnt -> this block's agent stores are at LLC
  if (th < 64) {
    if (th == 0) st_u32_agent(barr + bk * 16, epoch);
    if (bk == master) {
      for (;;) {
        u32 m0 = ld_u32_agent(barr + th * 16);
        u32 m1 = ld_u32_agent(barr + (th + 64) * 16);
        u32 m2 = ld_u32_agent(barr + (th + 128) * 16);
        u32 m3 = ld_u32_agent(barr + (th + 192) * 16);
        u32 mn01 = (m0 < m1) ? m0 : m1;
        u32 mn23 = (m2 < m3) ? m2 : m3;
        u32 mn = (mn01 < mn23) ? mn01 : mn23;
        if (__all(mn >= epoch)) break;
      }
      st_u32_agent(flg + th * 16, epoch);
      st_u32_agent(flg + (th + 64) * 16, epoch);
      st_u32_agent(flg + (th + 128) * 16, epoch);
      st_u32_agent(flg + (th + 192) * 16, epoch);
    } else if (th == 0) {
      while (ld_u32_agent(flg + bk * 16) < epoch) {}
    }
  }
  __syncthreads();
}

// ---------------- prep: LSTM weights -> bf16 A-fragment layout ----------------
__global__ void k_wfrag(const float* __restrict__ Wih, const float* __restrict__ Whh,
                        char* __restrict__ dst, int NT, int Kih) {
  int idx = blockIdx.x * 256 + threadIdx.x;   // (tile*NT + s)*64 + l
  int l = idx & 63;
  int st = idx >> 6;
  int s = st % NT, tile = st / NT;
  int r = l & 15, kg = l >> 4;
  int j = (r >> 2) * 1024 + tile * 4 + (r & 3);
  int k0 = s * 32 + kg * 8;
  const float* src = (k0 < Kih) ? (Wih + (size_t)j * Kih + k0)
                                : (Whh + (size_t)j * 1024 + (k0 - Kih));
  short8 v;
#pragma unroll
  for (int e = 0; e < 8; ++e) v[e] = (short)f2bf(src[e]);
  *(short8*)(dst + (size_t)idx * 16) = v;
}

// ---------------- prep: memW^T, combined biases, qW bf16 ----------------
__global__ void k_smallprep(const float* __restrict__ memW,
                            const float* __restrict__ abih, const float* __restrict__ abhh,
                            const float* __restrict__ dbih, const float* __restrict__ dbhh,
                            const float* __restrict__ qW, char* __restrict__ wsb) {
  int idx = blockIdx.x * 256 + threadIdx.x;
  if (idx < 65536) {
    int k = idx >> 7, d = idx & 127;
    ((float*)(wsb + OFF_MWT))[idx] = memW[d * 512 + k];
  } else if (idx < 69632) {
    int j = idx - 65536;
    ((float*)(wsb + OFF_BA))[j] = abih[j] + abhh[j];
  } else if (idx < 73728) {
    int j = idx - 69632;
    ((float*)(wsb + OFF_BD))[j] = dbih[j] + dbhh[j];
  } else if (idx < 204800) {
    int j = idx - 73728;
    ((u16*)(wsb + OFF_QWB))[j] = f2bf(qW[j]);
  }
}

// ---------------- prep: prenet -> bf16 B-fragment layout per step ----------------
__global__ void k_prenet(const float* __restrict__ dec_in,
                         const float* __restrict__ W1, const float* __restrict__ b1,
                         const float* __restrict__ W2, const float* __restrict__ b2,
                         char* __restrict__ wsb) {
  int s = blockIdx.x, b = blockIdx.y, th = threadIdx.x;
  __shared__ float frame[80];
  __shared__ float h1[256];
  if (th < 80) frame[th] = (s == 0) ? 0.f : dec_in[(b * 80 + th) * 64 + (s - 1)];
  __syncthreads();
  float a = b1[th];
  const float* w1r = W1 + th * 80;
  for (int m = 0; m < 80; ++m) a += w1r[m] * frame[m];
  h1[th] = fmaxf(a, 0.f);
  __syncthreads();
  float a2 = b2[th];
  const float* w2r = W2 + th * 256;
  for (int i = 0; i < 256; ++i) a2 += w2r[i] * h1[i];
  float pre = fmaxf(a2, 0.f);
  int k = th;
  ((u16*)(wsb + OFF_PREF))[(((size_t)s * 8 + (k >> 5)) * 64 + ((k >> 3) & 3) * 16 + b) * 8 + (k & 7)] = f2bf(pre);
}

// ---------------- prep: processed_memory pm[b][tt][d] ----------------
__global__ void k_pm(const float* __restrict__ memory, char* __restrict__ wsb) {
  int bk = blockIdx.x, th = threadIdx.x;
  int b = bk >> 4, t0 = (bk & 15) * 16;
  __shared__ float mrow[16 * 512];
  for (int i = 0; i < 8; ++i) {
    int fi4 = i * 256 + th;
    int tl = fi4 >> 7, k4 = (fi4 & 127) << 2;
    *(float4*)&mrow[tl * 512 + k4] =
        *(const float4*)&memory[((size_t)(b * 256 + t0 + tl)) * 512 + k4];
  }
  __syncthreads();
  int d = th & 127, tl0 = th >> 7;
  float acc[8] = {};
  const float* mWT = (const float*)(wsb + OFF_MWT);
  float* pmw = (float*)(wsb + OFF_PM);
  for (int k = 0; k < 512; ++k) {
    float w = mWT[k * 128 + d];
#pragma unroll
    for (int i = 0; i < 8; ++i) acc[i] += w * mrow[(tl0 + i * 2) * 512 + k];
  }
  for (int i = 0; i < 8; ++i)
    pmw[((size_t)(b * 256 + t0 + tl0 + i * 2)) * 128 + d] = acc[i];
}

struct KParams {
  const float* memory;
  const int* mlen;
  const float* convW;
  const float* ldW;
  const float* attnv;
  const float* projW;
  const float* projb;
  const float* gateW;
  const float* gateb;
  char* wsb;
  float* out;
};

// ---------------- main persistent kernel ----------------
// Epoch 1 (loop t): attn-LSTM(t) on blocks 0..127; conv(t) on blocks 0..15
//   (own-LDS aw state); dec-LSTM(t-1) on blocks 128..255 (weights in VGPRs).
// Epoch 2: phase-B attention(t) on blocks 0..15 only.
// Barrier masters: e1 -> 255 (dec, finishes early); e2 -> 100 (idle in e2).
__global__ void __launch_bounds__(512, 1) k_main(KParams p) {
  const int th = threadIdx.x;
  const int bk = blockIdx.x;
  char* wsb = p.wsb;
  const int l = th & 63, w = th >> 6;
  u32* barr = (u32*)(wsb + OFF_BAR);
  u32* flg  = (u32*)(wsb + OFF_BAR + 16384);
  u32 ep = 0;

  __shared__ float smC[4608];
  __shared__ float s2q[128], s2v[128];
  __shared__ float s2ldw[4608];               // [128][36]
  __shared__ float s_conv[9216];              // [256][36]
  __shared__ __align__(16) float s2ah[1024];
  __shared__ float s_e[256], s3wr[4];
  __shared__ float s1cw[1984];                // convW 32*62
  __shared__ float s_aw[256], s_awc[256];     // persistent per-batch attn state

  const float* pm = (const float*)(wsb + OFF_PM);
  const u16* qwb = (const u16*)(wsb + OFF_QWB);

  for (int i = th; i < 1984; i += 512) s1cw[i] = p.convW[i];
  for (int i = th; i < 4096; i += 512) s2ldw[(i >> 5) * 36 + (i & 31)] = p.ldW[i];
  if (th < 128) s2v[th] = p.attnv[th];
  if (th < 256) { s_aw[th] = 0.f; s_awc[th] = 0.f; }

  float bias_r;
  {
    int r = (th >> 4) & 15, rt2 = th >> 8;
    int tbase = (bk < 128) ? bk * 2 : (bk - 128) * 2;
    const float* bsrc = (const float*)(wsb + ((bk < 128) ? OFF_BA : OFF_BD));
    bias_r = bsrc[(r >> 2) * 1024 + (tbase + rt2) * 4 + (r & 3)];
  }
  int lenB = 0;
  if (bk < 16) lenB = p.mlen[bk];
  float cA = 0.f, cD = 0.f;

  const int rt = w & 1, kc = w >> 1;
  // step-invariant weights in registers: attn (blocks<128) and dec (blocks>=128)
  short8 afA[14], afD[20];
  if (bk < 128) {
    const char* wfa = wsb + OFF_WFA;
    int tIdx = bk * 2 + rt;
#pragma unroll
    for (int i = 0; i < 14; ++i)
      afA[i] = *(const short8*)(wfa + (((size_t)tIdx * 56 + (kc * 14 + i)) * 64 + l) * 16);
  } else {
    const char* wfd = wsb + OFF_WFD;
    int tIdx = (bk - 128) * 2 + rt;
#pragma unroll
    for (int i = 0; i < 20; ++i)
      afD[i] = *(const short8*)(wfd + (((size_t)tIdx * 80 + (kc * 20 + i)) * 64 + l) * 16);
  }
  __syncthreads();

  for (int t = 0; t <= 64; ++t) {
    // ================= epoch 1 =================
    if (bk < 16 && t < 64) {
      // location conv(t) from own-LDS aw/awc state -> s_conv (consumed in e2)
      int jmax = (lenB + 15) >> 4;
      for (int j = 0; j < jmax; ++j) {
        int idx = j * 512 + th, tt = idx >> 5, f = idx & 31;
        float a = 0.f;
        const float* w0 = s1cw + f * 62;
#pragma unroll
        for (int kk = 0; kk < 31; ++kk) {
          int pos = tt + kk - 15;
          bool ok = (pos >= 0 && pos < 256);
          float awv = ok ? s_aw[pos] : 0.f;
          float awcv = ok ? s_awc[pos] : 0.f;
          a += awv * w0[kk] + awcv * w0[31 + kk];
        }
        s_conv[tt * 36 + f] = a;
      }
    }
    if (bk < 128 && t < 64) {
      // attn-LSTM(t): 32 gate-rows per block
      f32x4 acc = {0.f, 0.f, 0.f, 0.f};
#pragma unroll
      for (int i = 0; i < 14; ++i) {
        int kt = kc * 14 + i;
        const char* src;
        if (kt < 8)       src = wsb + OFF_PREF + (((size_t)t * 8 + kt) * 64 + l) * 16;
        else if (kt < 24) src = wsb + OFF_CTXFD + (((size_t)t * 16 + (kt - 8)) * 64 + l) * 16;
        else              src = wsb + OFF_AHFD + (((size_t)t * 32 + (kt - 24)) * 64 + l) * 16;
        short8 bv = ld_frag_nt(src);
        acc = __builtin_amdgcn_mfma_f32_16x16x32_bf16(afA[i], bv, acc, 0, 0, 0);
      }
#pragma unroll
      for (int r4 = 0; r4 < 4; ++r4)
        smC[w * 256 + ((l >> 4) * 4 + r4) * 16 + (l & 15)] = acc[r4];
      __syncthreads();
      {
        int rt2 = th >> 8, r = (th >> 4) & 15, b2 = th & 15;
        float s = 0.f;
#pragma unroll
        for (int q = 0; q < 4; ++q) s += smC[(q * 2 + rt2) * 256 + r * 16 + b2];
        smC[4096 + th] = s + bias_r;
      }
      __syncthreads();
      if (th < 128) {
        int b = th & 15, lu = th >> 4;
        int rt3 = lu >> 2, ul = lu & 3;
        int u = (bk * 2 + rt3) * 4 + ul;
        float gi = smC[4096 + rt3 * 256 + ul * 16 + b];
        float gf = smC[4096 + rt3 * 256 + (4 + ul) * 16 + b];
        float gc = smC[4096 + rt3 * 256 + (8 + ul) * 16 + b];
        float go = smC[4096 + rt3 * 256 + (12 + ul) * 16 + b];
        float c2 = sigmf(gf) * cA + sigmf(gi) * tanhf(gc);
        float h2 = sigmf(go) * tanhf(c2);
        cA = c2;
        st_u16_agent((u16*)(wsb + OFF_AHFD) +
                     ((((size_t)(t + 1) * 32 + (u >> 5)) * 64 + ((u >> 3) & 3) * 16 + b) * 8 + (u & 7)),
                     f2bf(h2));
      }
    } else if (bk >= 128 && t >= 1) {
      // dec-LSTM(t-1): inputs all published before previous e2 barrier
      f32x4 acc = {0.f, 0.f, 0.f, 0.f};
#pragma unroll
      for (int i = 0; i < 20; ++i) {
        int kt = kc * 20 + i;
        const char* src;
        if (kt < 32)      src = wsb + OFF_AHFD + (((size_t)t * 32 + kt) * 64 + l) * 16;
        else if (kt < 48) src = wsb + OFF_CTXFD + (((size_t)t * 16 + (kt - 32)) * 64 + l) * 16;
        else              src = wsb + OFF_DHFD + (((size_t)(t - 1) * 32 + (kt - 48)) * 64 + l) * 16;
        short8 bv = ld_frag_nt(src);
        acc = __builtin_amdgcn_mfma_f32_16x16x32_bf16(afD[i], bv, acc, 0, 0, 0);
      }
#pragma unroll
      for (int r4 = 0; r4 < 4; ++r4)
        smC[w * 256 + ((l >> 4) * 4 + r4) * 16 + (l & 15)] = acc[r4];
      __syncthreads();
      {
        int rt2 = th >> 8, r = (th >> 4) & 15, b2 = th & 15;
        float s = 0.f;
#pragma unroll
        for (int q = 0; q < 4; ++q) s += smC[(q * 2 + rt2) * 256 + r * 16 + b2];
        smC[4096 + th] = s + bias_r;
      }
      __syncthreads();
      if (th < 128) {
        int b = th & 15, lu = th >> 4;
        int rt3 = lu >> 2, ul = lu & 3;
        int u = ((bk - 128) * 2 + rt3) * 4 + ul;
        float gi = smC[4096 + rt3 * 256 + ul * 16 + b];
        float gf = smC[4096 + rt3 * 256 + (4 + ul) * 16 + b];
        float gc = smC[4096 + rt3 * 256 + (8 + ul) * 16 + b];
        float go = smC[4096 + rt3 * 256 + (12 + ul) * 16 + b];
        float c2 = sigmf(gf) * cD + sigmf(gi) * tanhf(gc);
        float h2 = sigmf(go) * tanhf(c2);
        cD = c2;
        st_f32_agent((float*)(wsb + OFF_DHF) + ((size_t)t * 1024 + u) * 16 + b, h2);
        st_u16_agent((u16*)(wsb + OFF_DHFD) +
                     ((((size_t)t * 32 + (u >> 5)) * 64 + ((u >> 3) & 3) * 16 + b) * 8 + (u & 7)),
                     f2bf(h2));
      }
    }
    gbar(barr, flg, bk, th, ++ep, 255);

    // ================= epoch 2: phase-B attention(t) on blocks 0..15 ============
    if (t < 64) {
      if (bk < 16) {
        const int b = bk;
        if (th < 128) {   // stage ah(t) from AHFD[t+1] (NT, virgin)
          int o = th;
          short8 v = ld_frag_nt(wsb + OFF_AHFD +
                      (((size_t)(t + 1) * 32 + (o >> 2)) * 64 + (o & 3) * 16 + b) * 16);
#pragma unroll
          for (int e = 0; e < 8; ++e) s2ah[o * 8 + e] = bf2f((u16)v[e]);
        }
        __syncthreads();
        {  // query partials
          int d = th & 127, part = th >> 7;
          const u16* qr = qwb + d * 1024 + part * 256;
          const float* ah = s2ah + part * 256;
          float qa = 0.f;
          for (int kk = 0; kk < 256; kk += 8) {
            short8 v = *(const short8*)(qr + kk);
#pragma unroll
            for (int e = 0; e < 8; ++e) qa += bf2f((u16)v[e]) * ah[kk + e];
          }
          smC[part * 128 + d] = qa;
        }
        __syncthreads();
        if (th < 128) s2q[th] = smC[th] + smC[128 + th] + smC[256 + th] + smC[384 + th];
        __syncthreads();
        {  // energies: thread = (tt, d-half); s_conv filled in e1 (own LDS)
          int tt = th >> 1, dbase = (th & 1) << 6;
          float e = 0.f;
          if (tt < lenB) {
            float cvr[32];
            const float* cv = s_conv + tt * 36;
#pragma unroll
            for (int f = 0; f < 32; ++f) cvr[f] = cv[f];
            const float4* pmr = (const float4*)(pm + ((size_t)(b * 256 + tt)) * 128 + dbase);
#pragma unroll 4
            for (int j4 = 0; j4 < 16; ++j4) {
              float4 pv = pmr[j4];
              float pq[4] = {pv.x, pv.y, pv.z, pv.w};
#pragma unroll
              for (int jj = 0; jj < 4; ++jj) {
                int d2 = dbase + j4 * 4 + jj;
                float sacc = s2q[d2] + pq[jj];
                const float4* lw4 = (const float4*)(s2ldw + d2 * 36);
#pragma unroll
                for (int f4 = 0; f4 < 8; ++f4) {
                  float4 lw = lw4[f4];
                  sacc += cvr[f4 * 4] * lw.x + cvr[f4 * 4 + 1] * lw.y +
                          cvr[f4 * 4 + 2] * lw.z + cvr[f4 * 4 + 3] * lw.w;
                }
                e += s2v[d2] * tanh_fast(sacc);
              }
            }
          }
          e += __shfl_xor(e, 1);
          if ((th & 1) == 0) s_e[tt] = (tt < lenB) ? __expf(e) : 0.f;
        }
        __syncthreads();
        if (th < 256) {
          float v0 = s_e[th];
#pragma unroll
          for (int off = 32; off; off >>= 1) v0 += __shfl_xor(v0, off);
          if ((th & 63) == 0) s3wr[th >> 6] = v0;
        }
        __syncthreads();
        float rden = 1.f / (s3wr[0] + s3wr[1] + s3wr[2] + s3wr[3]);
        if (th < 256) {
          float a = s_e[th] * rden;
          s_aw[th] = a;
          s_awc[th] += a;
          p.out[82944 + ((size_t)(b * 64 + t)) * 256 + th] = a;
        }
        __syncthreads();
        {  // context: plain loads of memory (L2-resident per phase-B block)
          int dq = th & 127, tg = th >> 7;
          int d0 = dq * 4;
          float a0 = 0.f, a1 = 0.f, a2 = 0.f, a3 = 0.f;
          const float* mb = p.memory + ((size_t)b * 256) * 512 + d0;
          for (int tt = tg; tt < lenB; tt += 4) {
            float4 mv = *(const float4*)(mb + (size_t)tt * 512);
            float aw = s_aw[tt];
            a0 += aw * mv.x; a1 += aw * mv.y; a2 += aw * mv.z; a3 += aw * mv.w;
          }
          smC[tg * 512 + d0]     = a0;
          smC[tg * 512 + d0 + 1] = a1;
          smC[tg * 512 + d0 + 2] = a2;
          smC[tg * 512 + d0 + 3] = a3;
        }
        __syncthreads();
        {
          int d = th;
          float ctxv = smC[d] + smC[512 + d] + smC[1024 + d] + smC[1536 + d];
          st_f32_agent((float*)(wsb + OFF_CTXF) + ((size_t)(t + 1) * 512 + d) * 16 + b, ctxv);
          st_u16_agent((u16*)(wsb + OFF_CTXFD) +
                       ((((size_t)(t + 1) * 16 + (d >> 5)) * 64 + ((d >> 3) & 3) * 16 + b) * 8 + (d & 7)),
                       f2bf(ctxv));
        }
      }
      gbar(barr, flg, bk, th, ++ep, 100);
    }
  }

  // ================= epilogue: mel + gate projections =================
  {
    int t = bk & 63, pa = bk >> 6;
    const float* dh = (const float*)(wsb + OFF_DHF) + (size_t)(t + 1) * 16384;
    const float* cx = (const float*)(wsb + OFF_CTXF) + (size_t)(t + 1) * 8192;
    int lim = (pa == 3) ? 336 : 320;
    for (int idx = th; idx < lim; idx += 512) {
      if (idx < 320) {
        int mi = idx >> 4, b = idx & 15, m = pa * 20 + mi;
        const float* wr = p.projW + (size_t)m * 1536;
        float a0 = 0.f, a1 = 0.f;
#pragma unroll 8
        for (int k = 0; k < 1024; k += 2) { a0 += wr[k] * dh[k * 16 + b]; a1 += wr[k + 1] * dh[(k + 1) * 16 + b]; }
#pragma unroll 8
        for (int k = 0; k < 512; k += 2)  { a0 += wr[1024 + k] * cx[k * 16 + b]; a1 += wr[1025 + k] * cx[(k + 1) * 16 + b]; }
        p.out[((size_t)(b * 80 + m)) * 64 + t] = a0 + a1 + p.projb[m];
      } else {
        int b = idx - 320;
        float a0 = 0.f, a1 = 0.f;
#pragma unroll 8
        for (int k = 0; k < 1024; k += 2) { a0 += p.gateW[k] * dh[k * 16 + b]; a1 += p.gateW[k + 1] * dh[(k + 1) * 16 + b]; }
#pragma unroll 8
        for (int k = 0; k < 512; k += 2)  { a0 += p.gateW[1024 + k] * cx[k * 16 + b]; a1 += p.gateW[1025 + k] * cx[(k + 1) * 16 + b]; }
        p.out[81920 + b * 64 + t] = a0 + a1 + p.gateb[0];
      }
    }
  }
}

// ---------------- host launcher ----------------
extern "C" void kernel_launch(void* const* d_in, const int* in_sizes, int n_in,
                              void* d_out, int out_size, void* d_ws, size_t ws_size,
                              hipStream_t stream) {
  (void)in_sizes; (void)n_in; (void)out_size; (void)ws_size;
  const float* memory = (const float*)d_in[0];
  const float* dec_in = (const float*)d_in[1];
  const int*   mlen   = (const int*)d_in[2];
  const float* pW1    = (const float*)d_in[3];
  const float* pb1    = (const float*)d_in[4];
  const float* pW2    = (const float*)d_in[5];
  const float* pb2    = (const float*)d_in[6];
  const float* aWih   = (const float*)d_in[7];
  const float* aWhh   = (const float*)d_in[8];
  const float* abih   = (const float*)d_in[9];
  const float* abhh   = (const float*)d_in[10];
  const float* qW     = (const float*)d_in[11];
  const float* memW   = (const float*)d_in[12];
  const float* convW  = (const float*)d_in[13];
  const float* ldW    = (const float*)d_in[14];
  const float* attnv  = (const float*)d_in[15];
  const float* dWih   = (const float*)d_in[16];
  const float* dWhh   = (const float*)d_in[17];
  const float* dbih   = (const float*)d_in[18];
  const float* dbhh   = (const float*)d_in[19];
  const float* projW  = (const float*)d_in[20];
  const float* projb  = (const float*)d_in[21];
  const float* gateW  = (const float*)d_in[22];
  const float* gateb  = (const float*)d_in[23];
  char* wsb = (char*)d_ws;
  float* out = (float*)d_out;

  // zero slot-0 fragments (initial states) + barrier words
  hipMemsetAsync(wsb + OFF_AHFD, 0, 32768, stream);
  hipMemsetAsync(wsb + OFF_CTXFD, 0, 16384, stream);
  hipMemsetAsync(wsb + OFF_DHFD, 0, 32768, stream);
  hipMemsetAsync(wsb + OFF_BAR, 0, 32768, stream);

  hipLaunchKernelGGL(k_wfrag, dim3(3584), dim3(256), 0, stream, aWih, aWhh, wsb + OFF_WFA, 56, 768);
  hipLaunchKernelGGL(k_wfrag, dim3(5120), dim3(256), 0, stream, dWih, dWhh, wsb + OFF_WFD, 80, 1536);
  hipLaunchKernelGGL(k_smallprep, dim3(800), dim3(256), 0, stream, memW, abih, abhh, dbih, dbhh, qW, wsb);
  hipLaunchKernelGGL(k_prenet, dim3(64, 16), dim3(256), 0, stream, dec_in, pW1, pb1, pW2, pb2, wsb);
  hipLaunchKernelGGL(k_pm, dim3(256), dim3(256), 0, stream, memory, wsb);

  KParams p{memory, mlen, convW, ldW, attnv, projW, projb, gateW, gateb, wsb, out};
  void* args[] = { &p };
  hipLaunchCooperativeKernel((void*)k_main, dim3(256), dim3(512), args, 0, stream);
}

// Round 9
// 4039.194 us; speedup vs baseline: 1.3035x; 1.3035x over previous
//
#include <hip/hip_runtime.h>

typedef __attribute__((ext_vector_type(8))) short short8;
typedef __attribute__((ext_vector_type(4))) float f32x4;
typedef unsigned short u16;
typedef unsigned int u32;
typedef unsigned long long u64;

// Shapes: B=16, T_ENC=256, T_DEC=64, N_MEL=80, ENC=512, ARNN=DRNN=1024,
// PRENET=256, ATTN_DIM=128, LOC_F=32, LOC_K=31
// attn LSTM K = 1792 (56 tiles of 32); dec K = 2560 (80 tiles)
// MFMA 16x16x32 bf16; C/D: col=lane&15, row=(lane>>4)*4+reg  [HW-verified]
//
// Coherence: cross-block WRITES agent-scope (land in LLC). Cross-block READS
// are nontemporal loads (never allocate in L1/L2 -> can never hit a stale
// line; always served from LLC). Sync is point-to-point dataflow FLAGS
// (monotone per-producer epoch counters, packed lines, no barrier master).

// ---------------- workspace byte offsets ----------------
static constexpr size_t OFF_WFA   = 0;                 // 14,680,064
static constexpr size_t OFF_WFD   = 14680064;          // +20,971,520 = 35,651,584
static constexpr size_t OFF_PREF  = 35651584;          // +524,288
static constexpr size_t OFF_QWB   = 36175872;          // +262,144
static constexpr size_t OFF_MWT   = 36438016;          // +262,144
static constexpr size_t OFF_BA    = 36700160;          // +16,384
static constexpr size_t OFF_BD    = 36716544;          // +16,384
static constexpr size_t OFF_PM    = 36732928;          // +2,097,152  pm[b][tt][d] f32
static constexpr size_t OFF_CTXF  = 38830080;          // +2,129,920  65 slots f32
static constexpr size_t OFF_DHF   = 40960000;          // +4,259,840  65 slots f32
static constexpr size_t OFF_AHFD  = 45219840;          // +2,129,920  65 x 32KB frag
static constexpr size_t OFF_CTXFD = 47349760;          // +1,064,960  65 x 16KB frag
static constexpr size_t OFF_DHFD  = 48414720;          // +2,129,920  65 x 32KB frag
static constexpr size_t OFF_BAR   = 50544640;          // flags: A@0(512B) D@1024(512B) B@2048(1KB)
static constexpr size_t OFF_END   = 50548736;

__device__ __forceinline__ float sigmf(float x) { return 1.f / (1.f + expf(-x)); }
__device__ __forceinline__ float tanh_fast(float x) {
  float e2 = __expf(2.f * x);
  return 1.f - 2.f / (e2 + 1.f);
}
__device__ __forceinline__ u16 f2bf(float f) {
  u32 u = __float_as_uint(f);
  return (u16)((u + 0x7FFFu + ((u >> 16) & 1u)) >> 16);
}
__device__ __forceinline__ float bf2f(u16 x) { return __uint_as_float(((u32)x) << 16); }

// nontemporal coalesced fragment load (no cache allocation; served by LLC)
__device__ __forceinline__ short8 ld_frag_nt(const void* p) {
  const u64* q = (const u64*)p;
  u64 lo = __builtin_nontemporal_load(q);
  u64 hi = __builtin_nontemporal_load(q + 1);
  union { u64 q2[2]; short8 s; } u;
  u.q2[0] = lo; u.q2[1] = hi;
  return u.s;
}

// agent-scope helpers (UC path)
__device__ __forceinline__ void st_u16_agent(u16* p, u16 v) {
  __hip_atomic_store(p, v, __ATOMIC_RELAXED, __HIP_MEMORY_SCOPE_AGENT);
}
__device__ __forceinline__ void st_f32_agent(float* p, float v) {
  __hip_atomic_store(p, v, __ATOMIC_RELAXED, __HIP_MEMORY_SCOPE_AGENT);
}
__device__ __forceinline__ u32 ld_u32_agent(const u32* p) {
  return __hip_atomic_load(p, __ATOMIC_RELAXED, __HIP_MEMORY_SCOPE_AGENT);
}
__device__ __forceinline__ void st_u32_agent(u32* p, u32 v) {
  __hip_atomic_store(p, v, __ATOMIC_RELAXED, __HIP_MEMORY_SCOPE_AGENT);
}

// ---- dataflow waits: one wave polls, then __syncthreads releases block ----
// 128 packed u32 flags (8 lines): lanes cover [th] and [th+64]
__device__ __forceinline__ void wait_p128(const u32* F, u32 target, int th) {
  if (th < 64) {
    for (;;) {
      u32 v0 = ld_u32_agent(F + th);
      u32 v1 = ld_u32_agent(F + 64 + th);
      u32 mn = v0 < v1 ? v0 : v1;
      if (__all(mn >= target)) break;
      __builtin_amdgcn_s_sleep(2);
    }
  }
  __syncthreads();
}
// 16 flags strided one 64B line apart (spreads poll load across LLC banks)
__device__ __forceinline__ void wait_s16(const u32* F, u32 target, int th) {
  if (th < 64) {
    const u32* pf = F + (th & 15) * 16;
    for (;;) {
      u32 v = ld_u32_agent(pf);
      if (__all(v >= target)) break;
      __builtin_amdgcn_s_sleep(2);
    }
  }
  __syncthreads();
}

// ---------------- prep: LSTM weights -> bf16 A-fragment layout ----------------
__global__ void k_wfrag(const float* __restrict__ Wih, const float* __restrict__ Whh,
                        char* __restrict__ dst, int NT, int Kih) {
  int idx = blockIdx.x * 256 + threadIdx.x;   // (tile*NT + s)*64 + l
  int l = idx & 63;
  int st = idx >> 6;
  int s = st % NT, tile = st / NT;
  int r = l & 15, kg = l >> 4;
  int j = (r >> 2) * 1024 + tile * 4 + (r & 3);
  int k0 = s * 32 + kg * 8;
  const float* src = (k0 < Kih) ? (Wih + (size_t)j * Kih + k0)
                                : (Whh + (size_t)j * 1024 + (k0 - Kih));
  short8 v;
#pragma unroll
  for (int e = 0; e < 8; ++e) v[e] = (short)f2bf(src[e]);
  *(short8*)(dst + (size_t)idx * 16) = v;
}

// ---------------- prep: memW^T, combined biases, qW bf16 ----------------
__global__ void k_smallprep(const float* __restrict__ memW,
                            const float* __restrict__ abih, const float* __restrict__ abhh,
                            const float* __restrict__ dbih, const float* __restrict__ dbhh,
                            const float* __restrict__ qW, char* __restrict__ wsb) {
  int idx = blockIdx.x * 256 + threadIdx.x;
  if (idx < 65536) {
    int k = idx >> 7, d = idx & 127;
    ((float*)(wsb + OFF_MWT))[idx] = memW[d * 512 + k];
  } else if (idx < 69632) {
    int j = idx - 65536;
    ((float*)(wsb + OFF_BA))[j] = abih[j] + abhh[j];
  } else if (idx < 73728) {
    int j = idx - 69632;
    ((float*)(wsb + OFF_BD))[j] = dbih[j] + dbhh[j];
  } else if (idx < 204800) {
    int j = idx - 73728;
    ((u16*)(wsb + OFF_QWB))[j] = f2bf(qW[j]);
  }
}

// ---------------- prep: prenet -> bf16 B-fragment layout per step ----------------
__global__ void k_prenet(const float* __restrict__ dec_in,
                         const float* __restrict__ W1, const float* __restrict__ b1,
                         const float* __restrict__ W2, const float* __restrict__ b2,
                         char* __restrict__ wsb) {
  int s = blockIdx.x, b = blockIdx.y, th = threadIdx.x;
  __shared__ float frame[80];
  __shared__ float h1[256];
  if (th < 80) frame[th] = (s == 0) ? 0.f : dec_in[(b * 80 + th) * 64 + (s - 1)];
  __syncthreads();
  float a = b1[th];
  const float* w1r = W1 + th * 80;
  for (int m = 0; m < 80; ++m) a += w1r[m] * frame[m];
  h1[th] = fmaxf(a, 0.f);
  __syncthreads();
  float a2 = b2[th];
  const float* w2r = W2 + th * 256;
  for (int i = 0; i < 256; ++i) a2 += w2r[i] * h1[i];
  float pre = fmaxf(a2, 0.f);
  int k = th;
  ((u16*)(wsb + OFF_PREF))[(((size_t)s * 8 + (k >> 5)) * 64 + ((k >> 3) & 3) * 16 + b) * 8 + (k & 7)] = f2bf(pre);
}

// ---------------- prep: processed_memory pm[b][tt][d] ----------------
__global__ void k_pm(const float* __restrict__ memory, char* __restrict__ wsb) {
  int bk = blockIdx.x, th = threadIdx.x;
  int b = bk >> 4, t0 = (bk & 15) * 16;
  __shared__ float mrow[16 * 512];
  for (int i = 0; i < 8; ++i) {
    int fi4 = i * 256 + th;
    int tl = fi4 >> 7, k4 = (fi4 & 127) << 2;
    *(float4*)&mrow[tl * 512 + k4] =
        *(const float4*)&memory[((size_t)(b * 256 + t0 + tl)) * 512 + k4];
  }
  __syncthreads();
  int d = th & 127, tl0 = th >> 7;
  float acc[8] = {};
  const float* mWT = (const float*)(wsb + OFF_MWT);
  float* pmw = (float*)(wsb + OFF_PM);
  for (int k = 0; k < 512; ++k) {
    float w = mWT[k * 128 + d];
#pragma unroll
    for (int i = 0; i < 8; ++i) acc[i] += w * mrow[(tl0 + i * 2) * 512 + k];
  }
  for (int i = 0; i < 8; ++i)
    pmw[((size_t)(b * 256 + t0 + tl0 + i * 2)) * 128 + d] = acc[i];
}

struct KParams {
  const float* memory;
  const int* mlen;
  const float* convW;
  const float* ldW;
  const float* attnv;
  const float* projW;
  const float* projb;
  const float* gateW;
  const float* gateb;
  char* wsb;
  float* out;
};

// dec-LSTM step td = t-1 (slot convention: reads AHFD[t], CTXFD[t], DHFD[t-1];
// writes DHF[t], DHFD[t]). Weights streamed from L2 (read-only, plain loads).
__device__ __forceinline__ void run_dec(char* wsb, int t, int tb, int th, int l, int w,
                                        int rt, int kc, float biasD_r, float& cD,
                                        float* smC) {
  const char* wfd = wsb + OFF_WFD;
  int tIdx = tb * 2 + rt;
  f32x4 acc = {0.f, 0.f, 0.f, 0.f};
#pragma unroll
  for (int i = 0; i < 20; ++i) {
    int kt = kc * 20 + i;
    short8 av = *(const short8*)(wfd + (((size_t)tIdx * 80 + kt) * 64 + l) * 16);
    const char* src;
    if (kt < 32)      src = wsb + OFF_AHFD + (((size_t)t * 32 + kt) * 64 + l) * 16;
    else if (kt < 48) src = wsb + OFF_CTXFD + (((size_t)t * 16 + (kt - 32)) * 64 + l) * 16;
    else              src = wsb + OFF_DHFD + (((size_t)(t - 1) * 32 + (kt - 48)) * 64 + l) * 16;
    short8 bv = ld_frag_nt(src);
    acc = __builtin_amdgcn_mfma_f32_16x16x32_bf16(av, bv, acc, 0, 0, 0);
  }
#pragma unroll
  for (int r4 = 0; r4 < 4; ++r4)
    smC[w * 256 + ((l >> 4) * 4 + r4) * 16 + (l & 15)] = acc[r4];
  __syncthreads();
  {
    int rt2 = th >> 8, r = (th >> 4) & 15, b2 = th & 15;
    float s = 0.f;
#pragma unroll
    for (int q = 0; q < 4; ++q) s += smC[(q * 2 + rt2) * 256 + r * 16 + b2];
    smC[4096 + th] = s + biasD_r;
  }
  __syncthreads();
  if (th < 128) {
    int b = th & 15, lu = th >> 4;
    int rt3 = lu >> 2, ul = lu & 3;
    int u = (tb * 2 + rt3) * 4 + ul;
    float gi = smC[4096 + rt3 * 256 + ul * 16 + b];
    float gf = smC[4096 + rt3 * 256 + (4 + ul) * 16 + b];
    float gc = smC[4096 + rt3 * 256 + (8 + ul) * 16 + b];
    float go = smC[4096 + rt3 * 256 + (12 + ul) * 16 + b];
    float c2 = sigmf(gf) * cD + sigmf(gi) * tanhf(gc);
    float h2 = sigmf(go) * tanhf(c2);
    cD = c2;
    st_f32_agent((float*)(wsb + OFF_DHF) + ((size_t)t * 1024 + u) * 16 + b, h2);
    st_u16_agent((u16*)(wsb + OFF_DHFD) +
                 ((((size_t)t * 32 + (u >> 5)) * 64 + ((u >> 3) & 3) * 16 + b) * 8 + (u & 7)),
                 f2bf(h2));
  }
}

// ---------------- main persistent kernel (dataflow, no barriers) ---------------
// Roles: bk 0..15: conv(t) + phase-B(t), publish B-flag.
//        bk 16..143: attn(t) publish A-flag; then dec(t-1) publish D-flag.
//        bk 144..255: idle; wait final flags; epilogue (all blocks).
__global__ void __launch_bounds__(512, 1) k_main(KParams p) {
  const int th = threadIdx.x;
  const int bk = blockIdx.x;
  char* wsb = p.wsb;
  const int l = th & 63, w = th >> 6;
  u32* Af = (u32*)(wsb + OFF_BAR);            // 128 packed
  u32* Df = (u32*)(wsb + OFF_BAR + 1024);     // 128 packed
  u32* Bf = (u32*)(wsb + OFF_BAR + 2048);     // 16 strided (x16 u32)

  __shared__ float smC[4608];
  __shared__ float s2q[128], s2v[128];
  __shared__ float s2ldw[4608];               // [128][36]
  __shared__ float s_conv[9216];              // [256][36]
  __shared__ __align__(16) float s2ah[1024];
  __shared__ float s_e[256], s3wr[4];
  __shared__ float s1cw[1984];                // convW 32*62
  __shared__ float s_aw[256], s_awc[256];     // per-b attention state (blocks 0..15)

  const float* pm = (const float*)(wsb + OFF_PM);
  const u16* qwb = (const u16*)(wsb + OFF_QWB);

  if (bk < 16) {
    for (int i = th; i < 1984; i += 512) s1cw[i] = p.convW[i];
    for (int i = th; i < 4096; i += 512) s2ldw[(i >> 5) * 36 + (i & 31)] = p.ldW[i];
    if (th < 128) s2v[th] = p.attnv[th];
    if (th < 256) { s_aw[th] = 0.f; s_awc[th] = 0.f; }
  }

  float biasA_r = 0.f, biasD_r = 0.f;
  if (bk >= 16 && bk < 144) {
    int r = (th >> 4) & 15, rt2 = th >> 8, tbase = (bk - 16) * 2;
    biasA_r = ((const float*)(wsb + OFF_BA))[(r >> 2) * 1024 + (tbase + rt2) * 4 + (r & 3)];
    biasD_r = ((const float*)(wsb + OFF_BD))[(r >> 2) * 1024 + (tbase + rt2) * 4 + (r & 3)];
  }
  int lenB = 0;
  if (bk < 16) lenB = p.mlen[bk];
  float cA = 0.f, cD = 0.f;

  const int rt = w & 1, kc = w >> 1;
  short8 afA[14];
  if (bk >= 16 && bk < 144) {
    const char* wfa = wsb + OFF_WFA;
    int tIdx = (bk - 16) * 2 + rt;
#pragma unroll
    for (int i = 0; i < 14; ++i)
      afA[i] = *(const short8*)(wfa + (((size_t)tIdx * 56 + (kc * 14 + i)) * 64 + l) * 16);
  }
  __syncthreads();

  if (bk >= 16 && bk < 144) {
    // ============== attn + dec pipeline ==============
    const int tb = bk - 16;
    for (int t = 0; t < 64; ++t) {
      wait_s16(Bf, (u32)t, th);                 // ctx(t-1) published (trivial at t=0)
      {  // attn-LSTM(t)
        f32x4 acc = {0.f, 0.f, 0.f, 0.f};
#pragma unroll
        for (int i = 0; i < 14; ++i) {
          int kt = kc * 14 + i;
          const char* src;
          if (kt < 8)       src = wsb + OFF_PREF + (((size_t)t * 8 + kt) * 64 + l) * 16;
          else if (kt < 24) src = wsb + OFF_CTXFD + (((size_t)t * 16 + (kt - 8)) * 64 + l) * 16;
          else              src = wsb + OFF_AHFD + (((size_t)t * 32 + (kt - 24)) * 64 + l) * 16;
          short8 bv = ld_frag_nt(src);
          acc = __builtin_amdgcn_mfma_f32_16x16x32_bf16(afA[i], bv, acc, 0, 0, 0);
        }
#pragma unroll
        for (int r4 = 0; r4 < 4; ++r4)
          smC[w * 256 + ((l >> 4) * 4 + r4) * 16 + (l & 15)] = acc[r4];
        __syncthreads();
        {
          int rt2 = th >> 8, r = (th >> 4) & 15, b2 = th & 15;
          float s = 0.f;
#pragma unroll
          for (int q = 0; q < 4; ++q) s += smC[(q * 2 + rt2) * 256 + r * 16 + b2];
          smC[4096 + th] = s + biasA_r;
        }
        __syncthreads();
        if (th < 128) {
          int b = th & 15, lu = th >> 4;
          int rt3 = lu >> 2, ul = lu & 3;
          int u = (tb * 2 + rt3) * 4 + ul;
          float gi = smC[4096 + rt3 * 256 + ul * 16 + b];
          float gf = smC[4096 + rt3 * 256 + (4 + ul) * 16 + b];
          float gc = smC[4096 + rt3 * 256 + (8 + ul) * 16 + b];
          float go = smC[4096 + rt3 * 256 + (12 + ul) * 16 + b];
          float c2 = sigmf(gf) * cA + sigmf(gi) * tanhf(gc);
          float h2 = sigmf(go) * tanhf(c2);
          cA = c2;
          st_u16_agent((u16*)(wsb + OFF_AHFD) +
                       ((((size_t)(t + 1) * 32 + (u >> 5)) * 64 + ((u >> 3) & 3) * 16 + b) * 8 + (u & 7)),
                       f2bf(h2));
        }
      }
      __syncthreads();                          // drain frag stores (per-wave vmcnt)
      if (th == 0) st_u32_agent(Af + tb, (u32)(t + 1));
      if (t >= 1) {
        wait_p128(Df, (u32)(t - 1), th);        // dh(t-2) published (usually instant)
        run_dec(wsb, t, tb, th, l, w, rt, kc, biasD_r, cD, smC);
        __syncthreads();
        if (th == 0) st_u32_agent(Df + tb, (u32)t);
      }
    }
    // tail: dec(63)
    wait_s16(Bf, 64u, th);
    wait_p128(Df, 63u, th);
    run_dec(wsb, 64, tb, th, l, w, rt, kc, biasD_r, cD, smC);
    __syncthreads();
    if (th == 0) st_u32_agent(Df + tb, 64u);
  } else if (bk < 16) {
    // ============== conv + phase-B pipeline ==============
    const int b = bk;
    for (int t = 0; t < 64; ++t) {
      {  // conv(t) from own-LDS aw/awc (aw(t-1))
        int jmax = (lenB + 15) >> 4;
        for (int j = 0; j < jmax; ++j) {
          int idx = j * 512 + th, tt = idx >> 5, f = idx & 31;
          float a = 0.f;
          const float* w0 = s1cw + f * 62;
#pragma unroll
          for (int kk = 0; kk < 31; ++kk) {
            int pos = tt + kk - 15;
            bool ok = (pos >= 0 && pos < 256);
            float awv = ok ? s_aw[pos] : 0.f;
            float awcv = ok ? s_awc[pos] : 0.f;
            a += awv * w0[kk] + awcv * w0[31 + kk];
          }
          s_conv[tt * 36 + f] = a;
        }
      }
      wait_p128(Af, (u32)(t + 1), th);          // ah(t) published (also fences s_conv)
      if (th < 128) {   // stage ah(t) from AHFD[t+1] (NT)
        int o = th;
        short8 v = ld_frag_nt(wsb + OFF_AHFD +
                    (((size_t)(t + 1) * 32 + (o >> 2)) * 64 + (o & 3) * 16 + b) * 16);
#pragma unroll
        for (int e = 0; e < 8; ++e) s2ah[o * 8 + e] = bf2f((u16)v[e]);
      }
      __syncthreads();
      {  // query partials
        int d = th & 127, part = th >> 7;
        const u16* qr = qwb + d * 1024 + part * 256;
        const float* ah = s2ah + part * 256;
        float qa = 0.f;
        for (int kk = 0; kk < 256; kk += 8) {
          short8 v = *(const short8*)(qr + kk);
#pragma unroll
          for (int e = 0; e < 8; ++e) qa += bf2f((u16)v[e]) * ah[kk + e];
        }
        smC[part * 128 + d] = qa;
      }
      __syncthreads();
      if (th < 128) s2q[th] = smC[th] + smC[128 + th] + smC[256 + th] + smC[384 + th];
      __syncthreads();
      {  // energies: thread = (tt, d-half)
        int tt = th >> 1, dbase = (th & 1) << 6;
        float e = 0.f;
        if (tt < lenB) {
          float cvr[32];
          const float* cv = s_conv + tt * 36;
#pragma unroll
          for (int f = 0; f < 32; ++f) cvr[f] = cv[f];
          const float4* pmr = (const float4*)(pm + ((size_t)(b * 256 + tt)) * 128 + dbase);
#pragma unroll 4
          for (int j4 = 0; j4 < 16; ++j4) {
            float4 pv = pmr[j4];
            float pq[4] = {pv.x, pv.y, pv.z, pv.w};
#pragma unroll
            for (int jj = 0; jj < 4; ++jj) {
              int d2 = dbase + j4 * 4 + jj;
              float sacc = s2q[d2] + pq[jj];
              const float4* lw4 = (const float4*)(s2ldw + d2 * 36);
#pragma unroll
              for (int f4 = 0; f4 < 8; ++f4) {
                float4 lw = lw4[f4];
                sacc += cvr[f4 * 4] * lw.x + cvr[f4 * 4 + 1] * lw.y +
                        cvr[f4 * 4 + 2] * lw.z + cvr[f4 * 4 + 3] * lw.w;
              }
              e += s2v[d2] * tanh_fast(sacc);
            }
          }
        }
        e += __shfl_xor(e, 1);
        if ((th & 1) == 0) s_e[tt] = (tt < lenB) ? __expf(e) : 0.f;
      }
      __syncthreads();
      if (th < 256) {
        float v0 = s_e[th];
#pragma unroll
        for (int off = 32; off; off >>= 1) v0 += __shfl_xor(v0, off);
        if ((th & 63) == 0) s3wr[th >> 6] = v0;
      }
      __syncthreads();
      float rden = 1.f / (s3wr[0] + s3wr[1] + s3wr[2] + s3wr[3]);
      if (th < 256) {
        float a = s_e[th] * rden;
        s_aw[th] = a;
        s_awc[th] += a;
        p.out[82944 + ((size_t)(b * 64 + t)) * 256 + th] = a;
      }
      __syncthreads();
      {  // context: plain loads of memory (read-only, L2-resident)
        int dq = th & 127, tg = th >> 7;
        int d0 = dq * 4;
        float a0 = 0.f, a1 = 0.f, a2 = 0.f, a3 = 0.f;
        const float* mb = p.memory + ((size_t)b * 256) * 512 + d0;
        for (int tt = tg; tt < lenB; tt += 4) {
          float4 mv = *(const float4*)(mb + (size_t)tt * 512);
          float aw = s_aw[tt];
          a0 += aw * mv.x; a1 += aw * mv.y; a2 += aw * mv.z; a3 += aw * mv.w;
        }
        smC[tg * 512 + d0]     = a0;
        smC[tg * 512 + d0 + 1] = a1;
        smC[tg * 512 + d0 + 2] = a2;
        smC[tg * 512 + d0 + 3] = a3;
      }
      __syncthreads();
      {
        int d = th;
        float ctxv = smC[d] + smC[512 + d] + smC[1024 + d] + smC[1536 + d];
        st_f32_agent((float*)(wsb + OFF_CTXF) + ((size_t)(t + 1) * 512 + d) * 16 + b, ctxv);
        st_u16_agent((u16*)(wsb + OFF_CTXFD) +
                     ((((size_t)(t + 1) * 16 + (d >> 5)) * 64 + ((d >> 3) & 3) * 16 + b) * 8 + (d & 7)),
                     f2bf(ctxv));
      }
      __syncthreads();                          // drain ctx stores
      if (th == 0) st_u32_agent(Bf + b * 16, (u32)(t + 1));
    }
  }

  // ================= final dataflow sync + epilogue =================
  wait_p128(Df, 64u, th);
  wait_s16(Bf, 64u, th);
  {
    int t = bk & 63, pa = bk >> 6;
    const float* dh = (const float*)(wsb + OFF_DHF) + (size_t)(t + 1) * 16384;
    const float* cx = (const float*)(wsb + OFF_CTXF) + (size_t)(t + 1) * 8192;
    int lim = (pa == 3) ? 336 : 320;
    for (int idx = th; idx < lim; idx += 512) {
      if (idx < 320) {
        int mi = idx >> 4, b = idx & 15, m = pa * 20 + mi;
        const float* wr = p.projW + (size_t)m * 1536;
        float a0 = 0.f, a1 = 0.f;
#pragma unroll 8
        for (int k = 0; k < 1024; k += 2) { a0 += wr[k] * dh[k * 16 + b]; a1 += wr[k + 1] * dh[(k + 1) * 16 + b]; }
#pragma unroll 8
        for (int k = 0; k < 512; k += 2)  { a0 += wr[1024 + k] * cx[k * 16 + b]; a1 += wr[1025 + k] * cx[(k + 1) * 16 + b]; }
        p.out[((size_t)(b * 80 + m)) * 64 + t] = a0 + a1 + p.projb[m];
      } else {
        int b = idx - 320;
        float a0 = 0.f, a1 = 0.f;
#pragma unroll 8
        for (int k = 0; k < 1024; k += 2) { a0 += p.gateW[k] * dh[k * 16 + b]; a1 += p.gateW[k + 1] * dh[(k + 1) * 16 + b]; }
#pragma unroll 8
        for (int k = 0; k < 512; k += 2)  { a0 += p.gateW[1024 + k] * cx[k * 16 + b]; a1 += p.gateW[1025 + k] * cx[(k + 1) * 16 + b]; }
        p.out[81920 + b * 64 + t] = a0 + a1 + p.gateb[0];
      }
    }
  }
}

// ---------------- host launcher ----------------
extern "C" void kernel_launch(void* const* d_in, const int* in_sizes, int n_in,
                              void* d_out, int out_size, void* d_ws, size_t ws_size,
                              hipStream_t stream) {
  (void)in_sizes; (void)n_in; (void)out_size; (void)ws_size;
  const float* memory = (const float*)d_in[0];
  const float* dec_in = (const float*)d_in[1];
  const int*   mlen   = (const int*)d_in[2];
  const float* pW1    = (const float*)d_in[3];
  const float* pb1    = (const float*)d_in[4];
  const float* pW2    = (const float*)d_in[5];
  const float* pb2    = (const float*)d_in[6];
  const float* aWih   = (const float*)d_in[7];
  const float* aWhh   = (const float*)d_in[8];
  const float* abih   = (const float*)d_in[9];
  const float* abhh   = (const float*)d_in[10];
  const float* qW     = (const float*)d_in[11];
  const float* memW   = (const float*)d_in[12];
  const float* convW  = (const float*)d_in[13];
  const float* ldW    = (const float*)d_in[14];
  const float* attnv  = (const float*)d_in[15];
  const float* dWih   = (const float*)d_in[16];
  const float* dWhh   = (const float*)d_in[17];
  const float* dbih   = (const float*)d_in[18];
  const float* dbhh   = (const float*)d_in[19];
  const float* projW  = (const float*)d_in[20];
  const float* projb  = (const float*)d_in[21];
  const float* gateW  = (const float*)d_in[22];
  const float* gateb  = (const float*)d_in[23];
  char* wsb = (char*)d_ws;
  float* out = (float*)d_out;

  // zero slot-0 fragments (initial states) + flag words (replay-safe)
  hipMemsetAsync(wsb + OFF_AHFD, 0, 32768, stream);
  hipMemsetAsync(wsb + OFF_CTXFD, 0, 16384, stream);
  hipMemsetAsync(wsb + OFF_DHFD, 0, 32768, stream);
  hipMemsetAsync(wsb + OFF_BAR, 0, 4096, stream);

  hipLaunchKernelGGL(k_wfrag, dim3(3584), dim3(256), 0, stream, aWih, aWhh, wsb + OFF_WFA, 56, 768);
  hipLaunchKernelGGL(k_wfrag, dim3(5120), dim3(256), 0, stream, dWih, dWhh, wsb + OFF_WFD, 80, 1536);
  hipLaunchKernelGGL(k_smallprep, dim3(800), dim3(256), 0, stream, memW, abih, abhh, dbih, dbhh, qW, wsb);
  hipLaunchKernelGGL(k_prenet, dim3(64, 16), dim3(256), 0, stream, dec_in, pW1, pb1, pW2, pb2, wsb);
  hipLaunchKernelGGL(k_pm, dim3(256), dim3(256), 0, stream, memory, wsb);

  KParams p{memory, mlen, convW, ldW, attnv, projW, projb, gateW, gateb, wsb, out};
  void* args[] = { &p };
  hipLaunchCooperativeKernel((void*)k_main, dim3(256), dim3(512), args, 0, stream);
}

// Round 10
// 2855.214 us; speedup vs baseline: 1.8440x; 1.4147x over previous
//
#include <hip/hip_runtime.h>

typedef __attribute__((ext_vector_type(8))) short short8;
typedef __attribute__((ext_vector_type(4))) float f32x4;
typedef unsigned short u16;
typedef unsigned int u32;
typedef unsigned long long u64;

// Shapes: B=16, T_ENC=256, T_DEC=64, N_MEL=80, ENC=512, ARNN=DRNN=1024,
// PRENET=256, ATTN_DIM=128, LOC_F=32, LOC_K=31
// attn LSTM K = 1792 (56 tiles of 32); dec K = 2560 (80 tiles)
// MFMA 16x16x32 bf16; C/D: col=lane&15, row=(lane>>4)*4+reg  [HW-verified]
//
// Coherence: cross-block WRITES agent-scope (land in LLC). Cross-block READS
// are nontemporal loads (never allocate in L1/L2 -> can never hit a stale
// line; always served from LLC). Sync is point-to-point dataflow FLAGS.
// Energies now MFMA: S = conv(256x32) @ ldw^T(32x128), ldw B-frags in VGPRs.

// ---------------- workspace byte offsets ----------------
static constexpr size_t OFF_WFA   = 0;                 // 14,680,064
static constexpr size_t OFF_WFD   = 14680064;          // +20,971,520 = 35,651,584
static constexpr size_t OFF_PREF  = 35651584;          // +524,288
static constexpr size_t OFF_QWB   = 36175872;          // +262,144
static constexpr size_t OFF_MWT   = 36438016;          // +262,144
static constexpr size_t OFF_BA    = 36700160;          // +16,384
static constexpr size_t OFF_BD    = 36716544;          // +16,384
static constexpr size_t OFF_PM    = 36732928;          // +2,097,152  pm[b][tt][d] f32
static constexpr size_t OFF_CTXF  = 38830080;          // +2,129,920  65 slots f32
static constexpr size_t OFF_DHF   = 40960000;          // +4,259,840  65 slots f32
static constexpr size_t OFF_AHFD  = 45219840;          // +2,129,920  65 x 32KB frag
static constexpr size_t OFF_CTXFD = 47349760;          // +1,064,960  65 x 16KB frag
static constexpr size_t OFF_DHFD  = 48414720;          // +2,129,920  65 x 32KB frag
static constexpr size_t OFF_BAR   = 50544640;          // flags: A@0(512B) D@1024(512B) B@2048(1KB)
static constexpr size_t OFF_END   = 50548736;

__device__ __forceinline__ float sigmf(float x) { return 1.f / (1.f + expf(-x)); }
__device__ __forceinline__ float tanh_fast(float x) {
  float e2 = __expf(2.f * x);
  return 1.f - 2.f / (e2 + 1.f);
}
__device__ __forceinline__ u16 f2bf(float f) {
  u32 u = __float_as_uint(f);
  return (u16)((u + 0x7FFFu + ((u >> 16) & 1u)) >> 16);
}
__device__ __forceinline__ float bf2f(u16 x) { return __uint_as_float(((u32)x) << 16); }

// nontemporal coalesced fragment load (no cache allocation; served by LLC)
__device__ __forceinline__ short8 ld_frag_nt(const void* p) {
  const u64* q = (const u64*)p;
  u64 lo = __builtin_nontemporal_load(q);
  u64 hi = __builtin_nontemporal_load(q + 1);
  union { u64 q2[2]; short8 s; } u;
  u.q2[0] = lo; u.q2[1] = hi;
  return u.s;
}

// agent-scope helpers (UC path)
__device__ __forceinline__ void st_u16_agent(u16* p, u16 v) {
  __hip_atomic_store(p, v, __ATOMIC_RELAXED, __HIP_MEMORY_SCOPE_AGENT);
}
__device__ __forceinline__ void st_f32_agent(float* p, float v) {
  __hip_atomic_store(p, v, __ATOMIC_RELAXED, __HIP_MEMORY_SCOPE_AGENT);
}
__device__ __forceinline__ u32 ld_u32_agent(const u32* p) {
  return __hip_atomic_load(p, __ATOMIC_RELAXED, __HIP_MEMORY_SCOPE_AGENT);
}
__device__ __forceinline__ void st_u32_agent(u32* p, u32 v) {
  __hip_atomic_store(p, v, __ATOMIC_RELAXED, __HIP_MEMORY_SCOPE_AGENT);
}

// ---- dataflow waits: one wave polls, then __syncthreads releases block ----
template <int SLP>
__device__ __forceinline__ void wait_p128(const u32* F, u32 target, int th) {
  if (th < 64) {
    for (;;) {
      u32 v0 = ld_u32_agent(F + th);
      u32 v1 = ld_u32_agent(F + 64 + th);
      u32 mn = v0 < v1 ? v0 : v1;
      if (__all(mn >= target)) break;
      __builtin_amdgcn_s_sleep(SLP);
    }
  }
  __syncthreads();
}
template <int SLP>
__device__ __forceinline__ void wait_s16(const u32* F, u32 target, int th) {
  if (th < 64) {
    const u32* pf = F + (th & 15) * 16;
    for (;;) {
      u32 v = ld_u32_agent(pf);
      if (__all(v >= target)) break;
      __builtin_amdgcn_s_sleep(SLP);
    }
  }
  __syncthreads();
}

// ---------------- prep: LSTM weights -> bf16 A-fragment layout ----------------
__global__ void k_wfrag(const float* __restrict__ Wih, const float* __restrict__ Whh,
                        char* __restrict__ dst, int NT, int Kih) {
  int idx = blockIdx.x * 256 + threadIdx.x;   // (tile*NT + s)*64 + l
  int l = idx & 63;
  int st = idx >> 6;
  int s = st % NT, tile = st / NT;
  int r = l & 15, kg = l >> 4;
  int j = (r >> 2) * 1024 + tile * 4 + (r & 3);
  int k0 = s * 32 + kg * 8;
  const float* src = (k0 < Kih) ? (Wih + (size_t)j * Kih + k0)
                                : (Whh + (size_t)j * 1024 + (k0 - Kih));
  short8 v;
#pragma unroll
  for (int e = 0; e < 8; ++e) v[e] = (short)f2bf(src[e]);
  *(short8*)(dst + (size_t)idx * 16) = v;
}

// ---------------- prep: memW^T, combined biases, qW bf16 ----------------
__global__ void k_smallprep(const float* __restrict__ memW,
                            const float* __restrict__ abih, const float* __restrict__ abhh,
                            const float* __restrict__ dbih, const float* __restrict__ dbhh,
                            const float* __restrict__ qW, char* __restrict__ wsb) {
  int idx = blockIdx.x * 256 + threadIdx.x;
  if (idx < 65536) {
    int k = idx >> 7, d = idx & 127;
    ((float*)(wsb + OFF_MWT))[idx] = memW[d * 512 + k];
  } else if (idx < 69632) {
    int j = idx - 65536;
    ((float*)(wsb + OFF_BA))[j] = abih[j] + abhh[j];
  } else if (idx < 73728) {
    int j = idx - 69632;
    ((float*)(wsb + OFF_BD))[j] = dbih[j] + dbhh[j];
  } else if (idx < 204800) {
    int j = idx - 73728;
    ((u16*)(wsb + OFF_QWB))[j] = f2bf(qW[j]);
  }
}

// ---------------- prep: prenet -> bf16 B-fragment layout per step ----------------
__global__ void k_prenet(const float* __restrict__ dec_in,
                         const float* __restrict__ W1, const float* __restrict__ b1,
                         const float* __restrict__ W2, const float* __restrict__ b2,
                         char* __restrict__ wsb) {
  int s = blockIdx.x, b = blockIdx.y, th = threadIdx.x;
  __shared__ float frame[80];
  __shared__ float h1[256];
  if (th < 80) frame[th] = (s == 0) ? 0.f : dec_in[(b * 80 + th) * 64 + (s - 1)];
  __syncthreads();
  float a = b1[th];
  const float* w1r = W1 + th * 80;
  for (int m = 0; m < 80; ++m) a += w1r[m] * frame[m];
  h1[th] = fmaxf(a, 0.f);
  __syncthreads();
  float a2 = b2[th];
  const float* w2r = W2 + th * 256;
  for (int i = 0; i < 256; ++i) a2 += w2r[i] * h1[i];
  float pre = fmaxf(a2, 0.f);
  int k = th;
  ((u16*)(wsb + OFF_PREF))[(((size_t)s * 8 + (k >> 5)) * 64 + ((k >> 3) & 3) * 16 + b) * 8 + (k & 7)] = f2bf(pre);
}

// ---------------- prep: processed_memory pm[b][tt][d] ----------------
__global__ void k_pm(const float* __restrict__ memory, char* __restrict__ wsb) {
  int bk = blockIdx.x, th = threadIdx.x;
  int b = bk >> 4, t0 = (bk & 15) * 16;
  __shared__ float mrow[16 * 512];
  for (int i = 0; i < 8; ++i) {
    int fi4 = i * 256 + th;
    int tl = fi4 >> 7, k4 = (fi4 & 127) << 2;
    *(float4*)&mrow[tl * 512 + k4] =
        *(const float4*)&memory[((size_t)(b * 256 + t0 + tl)) * 512 + k4];
  }
  __syncthreads();
  int d = th & 127, tl0 = th >> 7;
  float acc[8] = {};
  const float* mWT = (const float*)(wsb + OFF_MWT);
  float* pmw = (float*)(wsb + OFF_PM);
  for (int k = 0; k < 512; ++k) {
    float w = mWT[k * 128 + d];
#pragma unroll
    for (int i = 0; i < 8; ++i) acc[i] += w * mrow[(tl0 + i * 2) * 512 + k];
  }
  for (int i = 0; i < 8; ++i)
    pmw[((size_t)(b * 256 + t0 + tl0 + i * 2)) * 128 + d] = acc[i];
}

struct KParams {
  const float* memory;
  const int* mlen;
  const float* convW;
  const float* ldW;
  const float* attnv;
  const float* projW;
  const float* projb;
  const float* gateW;
  const float* gateb;
  char* wsb;
  float* out;
};

// dec-LSTM step td = t-1 (reads AHFD[t], CTXFD[t], DHFD[t-1]; writes DHF[t], DHFD[t])
__device__ __forceinline__ void run_dec(char* wsb, int t, int tb, int th, int l, int w,
                                        int rt, int kc, float biasD_r, float& cD,
                                        float* smC) {
  const char* wfd = wsb + OFF_WFD;
  int tIdx = tb * 2 + rt;
  f32x4 acc = {0.f, 0.f, 0.f, 0.f};
#pragma unroll
  for (int i = 0; i < 20; ++i) {
    int kt = kc * 20 + i;
    short8 av = *(const short8*)(wfd + (((size_t)tIdx * 80 + kt) * 64 + l) * 16);
    const char* src;
    if (kt < 32)      src = wsb + OFF_AHFD + (((size_t)t * 32 + kt) * 64 + l) * 16;
    else if (kt < 48) src = wsb + OFF_CTXFD + (((size_t)t * 16 + (kt - 32)) * 64 + l) * 16;
    else              src = wsb + OFF_DHFD + (((size_t)(t - 1) * 32 + (kt - 48)) * 64 + l) * 16;
    short8 bv = ld_frag_nt(src);
    acc = __builtin_amdgcn_mfma_f32_16x16x32_bf16(av, bv, acc, 0, 0, 0);
  }
#pragma unroll
  for (int r4 = 0; r4 < 4; ++r4)
    smC[w * 256 + ((l >> 4) * 4 + r4) * 16 + (l & 15)] = acc[r4];
  __syncthreads();
  {
    int rt2 = th >> 8, r = (th >> 4) & 15, b2 = th & 15;
    float s = 0.f;
#pragma unroll
    for (int q = 0; q < 4; ++q) s += smC[(q * 2 + rt2) * 256 + r * 16 + b2];
    smC[4096 + th] = s + biasD_r;
  }
  __syncthreads();
  if (th < 128) {
    int b = th & 15, lu = th >> 4;
    int rt3 = lu >> 2, ul = lu & 3;
    int u = (tb * 2 + rt3) * 4 + ul;
    float gi = smC[4096 + rt3 * 256 + ul * 16 + b];
    float gf = smC[4096 + rt3 * 256 + (4 + ul) * 16 + b];
    float gc = smC[4096 + rt3 * 256 + (8 + ul) * 16 + b];
    float go = smC[4096 + rt3 * 256 + (12 + ul) * 16 + b];
    float c2 = sigmf(gf) * cD + sigmf(gi) * tanhf(gc);
    float h2 = sigmf(go) * tanhf(c2);
    cD = c2;
    st_f32_agent((float*)(wsb + OFF_DHF) + ((size_t)t * 1024 + u) * 16 + b, h2);
    st_u16_agent((u16*)(wsb + OFF_DHFD) +
                 ((((size_t)t * 32 + (u >> 5)) * 64 + ((u >> 3) & 3) * 16 + b) * 8 + (u & 7)),
                 f2bf(h2));
  }
}

// ---------------- main persistent kernel (dataflow, no barriers) ---------------
// Roles: bk 0..15: conv(t) + phase-B(t), publish B-flag.
//        bk 16..143: attn(t) publish A-flag; then dec(t-1) publish D-flag.
//        bk 144..255: long-sleep idle; wait final flags; epilogue (all blocks).
__global__ void __launch_bounds__(512, 1) k_main(KParams p) {
  const int th = threadIdx.x;
  const int bk = blockIdx.x;
  char* wsb = p.wsb;
  const int l = th & 63, w = th >> 6;
  u32* Af = (u32*)(wsb + OFF_BAR);            // 128 packed
  u32* Df = (u32*)(wsb + OFF_BAR + 1024);     // 128 packed
  u32* Bf = (u32*)(wsb + OFF_BAR + 2048);     // 16 strided (x16 u32)

  __shared__ float smC[4608];
  __shared__ float s2q[128], s2v[128];
  __shared__ u16 s_convF[8192];               // conv bf16 A-frags: [16 tiles][64][8]
  __shared__ __align__(16) float s2ah[1024];
  __shared__ float s_e[256], s3wr[4];
  __shared__ float s1cw[1984];                // convW 32*62
  __shared__ float s_aw[256], s_awc[256];     // per-b attention state (blocks 0..15)

  const float* pm = (const float*)(wsb + OFF_PM);
  const u16* qwb = (const u16*)(wsb + OFF_QWB);

  if (bk < 16) {
    for (int i = th; i < 1984; i += 512) s1cw[i] = p.convW[i];
    for (int i = th; i < 4096; i += 512) ((u32*)s_convF)[i] = 0u;
    if (th < 128) s2v[th] = p.attnv[th];
    if (th < 256) { s_aw[th] = 0.f; s_awc[th] = 0.f; }
  }

  float biasA_r = 0.f, biasD_r = 0.f;
  if (bk >= 16 && bk < 144) {
    int r = (th >> 4) & 15, rt2 = th >> 8, tbase = (bk - 16) * 2;
    biasA_r = ((const float*)(wsb + OFF_BA))[(r >> 2) * 1024 + (tbase + rt2) * 4 + (r & 3)];
    biasD_r = ((const float*)(wsb + OFF_BD))[(r >> 2) * 1024 + (tbase + rt2) * 4 + (r & 3)];
  }
  int lenB = 0;
  if (bk < 16) lenB = p.mlen[bk];
  float cA = 0.f, cD = 0.f;

  const int rt = w & 1, kc = w >> 1;
  short8 afA[14];
  if (bk >= 16 && bk < 144) {
    const char* wfa = wsb + OFF_WFA;
    int tIdx = (bk - 16) * 2 + rt;
#pragma unroll
    for (int i = 0; i < 14; ++i)
      afA[i] = *(const short8*)(wfa + (((size_t)tIdx * 56 + (kc * 14 + i)) * 64 + l) * 16);
  }
  // ldw B-frags in registers (phase-B blocks): B[k=f][n=d], 8 d-tiles x k-tile of 32
  short8 ldwB[8];
  if (bk < 16) {
    int kg = l >> 4, dcol = l & 15;
#pragma unroll
    for (int dt = 0; dt < 8; ++dt) {
      short8 v;
#pragma unroll
      for (int e = 0; e < 8; ++e)
        v[e] = (short)f2bf(p.ldW[(dt * 16 + dcol) * 32 + kg * 8 + e]);
      ldwB[dt] = v;
    }
  }
  __syncthreads();

  if (bk >= 16 && bk < 144) {
    // ============== attn + dec pipeline ==============
    const int tb = bk - 16;
    for (int t = 0; t < 64; ++t) {
      wait_s16<4>(Bf, (u32)t, th);              // ctx(t-1) published
      {  // attn-LSTM(t)
        f32x4 acc = {0.f, 0.f, 0.f, 0.f};
#pragma unroll
        for (int i = 0; i < 14; ++i) {
          int kt = kc * 14 + i;
          const char* src;
          if (kt < 8)       src = wsb + OFF_PREF + (((size_t)t * 8 + kt) * 64 + l) * 16;
          else if (kt < 24) src = wsb + OFF_CTXFD + (((size_t)t * 16 + (kt - 8)) * 64 + l) * 16;
          else              src = wsb + OFF_AHFD + (((size_t)t * 32 + (kt - 24)) * 64 + l) * 16;
          short8 bv = ld_frag_nt(src);
          acc = __builtin_amdgcn_mfma_f32_16x16x32_bf16(afA[i], bv, acc, 0, 0, 0);
        }
#pragma unroll
        for (int r4 = 0; r4 < 4; ++r4)
          smC[w * 256 + ((l >> 4) * 4 + r4) * 16 + (l & 15)] = acc[r4];
        __syncthreads();
        {
          int rt2 = th >> 8, r = (th >> 4) & 15, b2 = th & 15;
          float s = 0.f;
#pragma unroll
          for (int q = 0; q < 4; ++q) s += smC[(q * 2 + rt2) * 256 + r * 16 + b2];
          smC[4096 + th] = s + biasA_r;
        }
        __syncthreads();
        if (th < 128) {
          int b = th & 15, lu = th >> 4;
          int rt3 = lu >> 2, ul = lu & 3;
          int u = (tb * 2 + rt3) * 4 + ul;
          float gi = smC[4096 + rt3 * 256 + ul * 16 + b];
          float gf = smC[4096 + rt3 * 256 + (4 + ul) * 16 + b];
          float gc = smC[4096 + rt3 * 256 + (8 + ul) * 16 + b];
          float go = smC[4096 + rt3 * 256 + (12 + ul) * 16 + b];
          float c2 = sigmf(gf) * cA + sigmf(gi) * tanhf(gc);
          float h2 = sigmf(go) * tanhf(c2);
          cA = c2;
          st_u16_agent((u16*)(wsb + OFF_AHFD) +
                       ((((size_t)(t + 1) * 32 + (u >> 5)) * 64 + ((u >> 3) & 3) * 16 + b) * 8 + (u & 7)),
                       f2bf(h2));
        }
      }
      __syncthreads();                          // drain frag stores
      if (th == 0) st_u32_agent(Af + tb, (u32)(t + 1));
      if (t >= 1) {
        wait_p128<4>(Df, (u32)(t - 1), th);
        run_dec(wsb, t, tb, th, l, w, rt, kc, biasD_r, cD, smC);
        __syncthreads();
        if (th == 0) st_u32_agent(Df + tb, (u32)t);
      }
    }
    // tail: dec(63)
    wait_s16<4>(Bf, 64u, th);
    wait_p128<4>(Df, 63u, th);
    run_dec(wsb, 64, tb, th, l, w, rt, kc, biasD_r, cD, smC);
    __syncthreads();
    if (th == 0) st_u32_agent(Df + tb, 64u);
  } else if (bk < 16) {
    // ============== conv + phase-B pipeline ==============
    const int b = bk;
    for (int t = 0; t < 64; ++t) {
      {  // conv(t) from own-LDS aw/awc -> bf16 A-frag layout in s_convF
        int jmax = (lenB + 15) >> 4;
        for (int j = 0; j < jmax; ++j) {
          int idx = j * 512 + th, tt = idx >> 5, f = idx & 31;
          float a = 0.f;
          const float* w0 = s1cw + f * 62;
#pragma unroll
          for (int kk = 0; kk < 31; ++kk) {
            int pos = tt + kk - 15;
            bool ok = (pos >= 0 && pos < 256);
            float awv = ok ? s_aw[pos] : 0.f;
            float awcv = ok ? s_awc[pos] : 0.f;
            a += awv * w0[kk] + awcv * w0[31 + kk];
          }
          s_convF[(tt >> 4) * 512 + ((f >> 3) * 16 + (tt & 15)) * 8 + (f & 7)] = f2bf(a);
        }
      }
      wait_p128<4>(Af, (u32)(t + 1), th);       // ah(t) published (fences s_convF too)
      if (th < 128) {   // stage ah(t) from AHFD[t+1] (NT)
        int o = th;
        short8 v = ld_frag_nt(wsb + OFF_AHFD +
                    (((size_t)(t + 1) * 32 + (o >> 2)) * 64 + (o & 3) * 16 + b) * 16);
#pragma unroll
        for (int e = 0; e < 8; ++e) s2ah[o * 8 + e] = bf2f((u16)v[e]);
      }
      __syncthreads();
      {  // query partials
        int d = th & 127, part = th >> 7;
        const u16* qr = qwb + d * 1024 + part * 256;
        const float* ah = s2ah + part * 256;
        float qa = 0.f;
        for (int kk = 0; kk < 256; kk += 8) {
          short8 v = *(const short8*)(qr + kk);
#pragma unroll
          for (int e = 0; e < 8; ++e) qa += bf2f((u16)v[e]) * ah[kk + e];
        }
        smC[part * 128 + d] = qa;
      }
      __syncthreads();
      if (th < 128) s2q[th] = smC[th] + smC[128 + th] + smC[256 + th] + smC[384 + th];
      __syncthreads();
      {  // energies via MFMA: wave w owns tt-tiles {2w, 2w+1}
#pragma unroll
        for (int tl = 0; tl < 2; ++tl) {
          int ttile = w * 2 + tl;
          short8 afc = *(const short8*)&s_convF[ttile * 512 + l * 8];
          int dcol = l & 15;
          float e0 = 0.f, e1 = 0.f, e2 = 0.f, e3 = 0.f;
          const float* pmb = pm + ((size_t)(b * 256 + ttile * 16 + (l >> 4) * 4)) * 128 + dcol;
#pragma unroll
          for (int dt = 0; dt < 8; ++dt) {
            f32x4 S = {0.f, 0.f, 0.f, 0.f};
            S = __builtin_amdgcn_mfma_f32_16x16x32_bf16(afc, ldwB[dt], S, 0, 0, 0);
            int d = dt * 16 + dcol;
            float qd = s2q[d], vd = s2v[d];
            e0 += vd * tanh_fast(qd + pmb[dt * 16 + 0 * 128] + S[0]);
            e1 += vd * tanh_fast(qd + pmb[dt * 16 + 1 * 128] + S[1]);
            e2 += vd * tanh_fast(qd + pmb[dt * 16 + 2 * 128] + S[2]);
            e3 += vd * tanh_fast(qd + pmb[dt * 16 + 3 * 128] + S[3]);
          }
#pragma unroll
          for (int off = 8; off; off >>= 1) {
            e0 += __shfl_xor(e0, off);
            e1 += __shfl_xor(e1, off);
            e2 += __shfl_xor(e2, off);
            e3 += __shfl_xor(e3, off);
          }
          if ((l & 15) == 0) {
            int tb0 = ttile * 16 + (l >> 4) * 4;
            s_e[tb0]     = (tb0     < lenB) ? __expf(e0) : 0.f;
            s_e[tb0 + 1] = (tb0 + 1 < lenB) ? __expf(e1) : 0.f;
            s_e[tb0 + 2] = (tb0 + 2 < lenB) ? __expf(e2) : 0.f;
            s_e[tb0 + 3] = (tb0 + 3 < lenB) ? __expf(e3) : 0.f;
          }
        }
      }
      __syncthreads();
      if (th < 256) {
        float v0 = s_e[th];
#pragma unroll
        for (int off = 32; off; off >>= 1) v0 += __shfl_xor(v0, off);
        if ((th & 63) == 0) s3wr[th >> 6] = v0;
      }
      __syncthreads();
      float rden = 1.f / (s3wr[0] + s3wr[1] + s3wr[2] + s3wr[3]);
      if (th < 256) {
        float a = s_e[th] * rden;
        s_aw[th] = a;
        s_awc[th] += a;
        p.out[82944 + ((size_t)(b * 64 + t)) * 256 + th] = a;
      }
      __syncthreads();
      {  // context: plain loads of memory (read-only, L2-resident)
        int dq = th & 127, tg = th >> 7;
        int d0 = dq * 4;
        float a0 = 0.f, a1 = 0.f, a2 = 0.f, a3 = 0.f;
        const float* mb = p.memory + ((size_t)b * 256) * 512 + d0;
        for (int tt = tg; tt < lenB; tt += 4) {
          float4 mv = *(const float4*)(mb + (size_t)tt * 512);
          float aw = s_aw[tt];
          a0 += aw * mv.x; a1 += aw * mv.y; a2 += aw * mv.z; a3 += aw * mv.w;
        }
        smC[tg * 512 + d0]     = a0;
        smC[tg * 512 + d0 + 1] = a1;
        smC[tg * 512 + d0 + 2] = a2;
        smC[tg * 512 + d0 + 3] = a3;
      }
      __syncthreads();
      {
        int d = th;
        float ctxv = smC[d] + smC[512 + d] + smC[1024 + d] + smC[1536 + d];
        st_f32_agent((float*)(wsb + OFF_CTXF) + ((size_t)(t + 1) * 512 + d) * 16 + b, ctxv);
        st_u16_agent((u16*)(wsb + OFF_CTXFD) +
                     ((((size_t)(t + 1) * 16 + (d >> 5)) * 64 + ((d >> 3) & 3) * 16 + b) * 8 + (d & 7)),
                     f2bf(ctxv));
      }
      __syncthreads();                          // drain ctx stores
      if (th == 0) st_u32_agent(Bf + b * 16, (u32)(t + 1));
    }
  }

  // ================= final dataflow sync + epilogue =================
  if (bk >= 144) {
    wait_p128<96>(Df, 64u, th);                 // long-sleep idle polling
    wait_s16<96>(Bf, 64u, th);
  } else {
    wait_p128<8>(Df, 64u, th);
    wait_s16<8>(Bf, 64u, th);
  }
  {
    int t = bk & 63, pa = bk >> 6;
    const float* dh = (const float*)(wsb + OFF_DHF) + (size_t)(t + 1) * 16384;
    const float* cx = (const float*)(wsb + OFF_CTXF) + (size_t)(t + 1) * 8192;
    int lim = (pa == 3) ? 336 : 320;
    for (int idx = th; idx < lim; idx += 512) {
      if (idx < 320) {
        int mi = idx >> 4, b = idx & 15, m = pa * 20 + mi;
        const float* wr = p.projW + (size_t)m * 1536;
        float a0 = 0.f, a1 = 0.f;
#pragma unroll 8
        for (int k = 0; k < 1024; k += 2) { a0 += wr[k] * dh[k * 16 + b]; a1 += wr[k + 1] * dh[(k + 1) * 16 + b]; }
#pragma unroll 8
        for (int k = 0; k < 512; k += 2)  { a0 += wr[1024 + k] * cx[k * 16 + b]; a1 += wr[1025 + k] * cx[(k + 1) * 16 + b]; }
        p.out[((size_t)(b * 80 + m)) * 64 + t] = a0 + a1 + p.projb[m];
      } else {
        int b = idx - 320;
        float a0 = 0.f, a1 = 0.f;
#pragma unroll 8
        for (int k = 0; k < 1024; k += 2) { a0 += p.gateW[k] * dh[k * 16 + b]; a1 += p.gateW[k + 1] * dh[(k + 1) * 16 + b]; }
#pragma unroll 8
        for (int k = 0; k < 512; k += 2)  { a0 += p.gateW[1024 + k] * cx[k * 16 + b]; a1 += p.gateW[1025 + k] * cx[(k + 1) * 16 + b]; }
        p.out[81920 + b * 64 + t] = a0 + a1 + p.gateb[0];
      }
    }
  }
}

// ---------------- host launcher ----------------
extern "C" void kernel_launch(void* const* d_in, const int* in_sizes, int n_in,
                              void* d_out, int out_size, void* d_ws, size_t ws_size,
                              hipStream_t stream) {
  (void)in_sizes; (void)n_in; (void)out_size; (void)ws_size;
  const float* memory = (const float*)d_in[0];
  const float* dec_in = (const float*)d_in[1];
  const int*   mlen   = (const int*)d_in[2];
  const float* pW1    = (const float*)d_in[3];
  const float* pb1    = (const float*)d_in[4];
  const float* pW2    = (const float*)d_in[5];
  const float* pb2    = (const float*)d_in[6];
  const float* aWih   = (const float*)d_in[7];
  const float* aWhh   = (const float*)d_in[8];
  const float* abih   = (const float*)d_in[9];
  const float* abhh   = (const float*)d_in[10];
  const float* qW     = (const float*)d_in[11];
  const float* memW   = (const float*)d_in[12];
  const float* convW  = (const float*)d_in[13];
  const float* ldW    = (const float*)d_in[14];
  const float* attnv  = (const float*)d_in[15];
  const float* dWih   = (const float*)d_in[16];
  const float* dWhh   = (const float*)d_in[17];
  const float* dbih   = (const float*)d_in[18];
  const float* dbhh   = (const float*)d_in[19];
  const float* projW  = (const float*)d_in[20];
  const float* projb  = (const float*)d_in[21];
  const float* gateW  = (const float*)d_in[22];
  const float* gateb  = (const float*)d_in[23];
  char* wsb = (char*)d_ws;
  float* out = (float*)d_out;

  // zero slot-0 fragments (initial states) + flag words (replay-safe)
  hipMemsetAsync(wsb + OFF_AHFD, 0, 32768, stream);
  hipMemsetAsync(wsb + OFF_CTXFD, 0, 16384, stream);
  hipMemsetAsync(wsb + OFF_DHFD, 0, 32768, stream);
  hipMemsetAsync(wsb + OFF_BAR, 0, 4096, stream);

  hipLaunchKernelGGL(k_wfrag, dim3(3584), dim3(256), 0, stream, aWih, aWhh, wsb + OFF_WFA, 56, 768);
  hipLaunchKernelGGL(k_wfrag, dim3(5120), dim3(256), 0, stream, dWih, dWhh, wsb + OFF_WFD, 80, 1536);
  hipLaunchKernelGGL(k_smallprep, dim3(800), dim3(256), 0, stream, memW, abih, abhh, dbih, dbhh, qW, wsb);
  hipLaunchKernelGGL(k_prenet, dim3(64, 16), dim3(256), 0, stream, dec_in, pW1, pb1, pW2, pb2, wsb);
  hipLaunchKernelGGL(k_pm, dim3(256), dim3(256), 0, stream, memory, wsb);

  KParams p{memory, mlen, convW, ldW, attnv, projW, projb, gateW, gateb, wsb, out};
  void* args[] = { &p };
  hipLaunchCooperativeKernel((void*)k_main, dim3(256), dim3(512), args, 0, stream);
}

// Round 11
// 2825.610 us; speedup vs baseline: 1.8633x; 1.0105x over previous
//
#include <hip/hip_runtime.h>

typedef __attribute__((ext_vector_type(8))) short short8;
typedef __attribute__((ext_vector_type(4))) float f32x4;
typedef unsigned short u16;
typedef unsigned int u32;
typedef unsigned long long u64;

// Shapes: B=16, T_ENC=256, T_DEC=64, N_MEL=80, ENC=512, ARNN=DRNN=1024,
// PRENET=256, ATTN_DIM=128, LOC_F=32, LOC_K=31
// attn LSTM K = 1792 (56 tiles of 32); dec K = 2560 (80 tiles)
// MFMA 16x16x32 bf16; C/D: col=lane&15, row=(lane>>4)*4+reg  [HW-verified]
//
// Coherence: cross-block WRITES agent-scope (land in LLC). Cross-block READS
// are nontemporal loads (never allocate in L1/L2 -> can never hit a stale
// line; always served from LLC). Sync is point-to-point dataflow FLAGS.
// Attn split: 40 "early" tiles (PREF+AHFD, depend only on ah(t-1)) run in
// phase-B's shadow; only 16 "late" CTXFD tiles sit on the critical path.

// ---------------- workspace byte offsets ----------------
static constexpr size_t OFF_WFA   = 0;                 // 14,680,064
static constexpr size_t OFF_WFD   = 14680064;          // +20,971,520 = 35,651,584
static constexpr size_t OFF_PREF  = 35651584;          // +524,288
static constexpr size_t OFF_QWB   = 36175872;          // +262,144
static constexpr size_t OFF_MWT   = 36438016;          // +262,144
static constexpr size_t OFF_BA    = 36700160;          // +16,384
static constexpr size_t OFF_BD    = 36716544;          // +16,384
static constexpr size_t OFF_PM    = 36732928;          // +2,097,152  pm[b][tt][d] f32
static constexpr size_t OFF_CTXF  = 38830080;          // +2,129,920  65 slots f32
static constexpr size_t OFF_DHF   = 40960000;          // +4,259,840  65 slots f32
static constexpr size_t OFF_AHFD  = 45219840;          // +2,129,920  65 x 32KB frag
static constexpr size_t OFF_CTXFD = 47349760;          // +1,064,960  65 x 16KB frag
static constexpr size_t OFF_DHFD  = 48414720;          // +2,129,920  65 x 32KB frag
static constexpr size_t OFF_BAR   = 50544640;          // flags: A@0(512B) D@1024(512B) B@2048(1KB)
static constexpr size_t OFF_END   = 50548736;

__device__ __forceinline__ float sigmf(float x) { return 1.f / (1.f + expf(-x)); }
__device__ __forceinline__ float tanh_fast(float x) {
  float e2 = __expf(2.f * x);
  return 1.f - 2.f / (e2 + 1.f);
}
__device__ __forceinline__ u16 f2bf(float f) {
  u32 u = __float_as_uint(f);
  return (u16)((u + 0x7FFFu + ((u >> 16) & 1u)) >> 16);
}
__device__ __forceinline__ float bf2f(u16 x) { return __uint_as_float(((u32)x) << 16); }

// nontemporal coalesced fragment load (no cache allocation; served by LLC)
__device__ __forceinline__ short8 ld_frag_nt(const void* p) {
  const u64* q = (const u64*)p;
  u64 lo = __builtin_nontemporal_load(q);
  u64 hi = __builtin_nontemporal_load(q + 1);
  union { u64 q2[2]; short8 s; } u;
  u.q2[0] = lo; u.q2[1] = hi;
  return u.s;
}

// agent-scope helpers (UC path)
__device__ __forceinline__ void st_u16_agent(u16* p, u16 v) {
  __hip_atomic_store(p, v, __ATOMIC_RELAXED, __HIP_MEMORY_SCOPE_AGENT);
}
__device__ __forceinline__ void st_f32_agent(float* p, float v) {
  __hip_atomic_store(p, v, __ATOMIC_RELAXED, __HIP_MEMORY_SCOPE_AGENT);
}
__device__ __forceinline__ u32 ld_u32_agent(const u32* p) {
  return __hip_atomic_load(p, __ATOMIC_RELAXED, __HIP_MEMORY_SCOPE_AGENT);
}
__device__ __forceinline__ void st_u32_agent(u32* p, u32 v) {
  __hip_atomic_store(p, v, __ATOMIC_RELAXED, __HIP_MEMORY_SCOPE_AGENT);
}

// ---- dataflow waits: one wave polls, then __syncthreads releases block ----
template <int SLP>
__device__ __forceinline__ void wait_p128(const u32* F, u32 target, int th) {
  if (th < 64) {
    for (;;) {
      u32 v0 = ld_u32_agent(F + th);
      u32 v1 = ld_u32_agent(F + 64 + th);
      u32 mn = v0 < v1 ? v0 : v1;
      if (__all(mn >= target)) break;
      __builtin_amdgcn_s_sleep(SLP);
    }
  }
  __syncthreads();
}
template <int SLP>
__device__ __forceinline__ void wait_s16(const u32* F, u32 target, int th) {
  if (th < 64) {
    const u32* pf = F + (th & 15) * 16;
    for (;;) {
      u32 v = ld_u32_agent(pf);
      if (__all(v >= target)) break;
      __builtin_amdgcn_s_sleep(SLP);
    }
  }
  __syncthreads();
}

// ---------------- prep: LSTM weights -> bf16 A-fragment layout ----------------
__global__ void k_wfrag(const float* __restrict__ Wih, const float* __restrict__ Whh,
                        char* __restrict__ dst, int NT, int Kih) {
  int idx = blockIdx.x * 256 + threadIdx.x;   // (tile*NT + s)*64 + l
  int l = idx & 63;
  int st = idx >> 6;
  int s = st % NT, tile = st / NT;
  int r = l & 15, kg = l >> 4;
  int j = (r >> 2) * 1024 + tile * 4 + (r & 3);
  int k0 = s * 32 + kg * 8;
  const float* src = (k0 < Kih) ? (Wih + (size_t)j * Kih + k0)
                                : (Whh + (size_t)j * 1024 + (k0 - Kih));
  short8 v;
#pragma unroll
  for (int e = 0; e < 8; ++e) v[e] = (short)f2bf(src[e]);
  *(short8*)(dst + (size_t)idx * 16) = v;
}

// ---------------- prep: memW^T, combined biases, qW bf16 ----------------
__global__ void k_smallprep(const float* __restrict__ memW,
                            const float* __restrict__ abih, const float* __restrict__ abhh,
                            const float* __restrict__ dbih, const float* __restrict__ dbhh,
                            const float* __restrict__ qW, char* __restrict__ wsb) {
  int idx = blockIdx.x * 256 + threadIdx.x;
  if (idx < 65536) {
    int k = idx >> 7, d = idx & 127;
    ((float*)(wsb + OFF_MWT))[idx] = memW[d * 512 + k];
  } else if (idx < 69632) {
    int j = idx - 65536;
    ((float*)(wsb + OFF_BA))[j] = abih[j] + abhh[j];
  } else if (idx < 73728) {
    int j = idx - 69632;
    ((float*)(wsb + OFF_BD))[j] = dbih[j] + dbhh[j];
  } else if (idx < 204800) {
    int j = idx - 73728;
    ((u16*)(wsb + OFF_QWB))[j] = f2bf(qW[j]);
  }
}

// ---------------- prep: prenet -> bf16 B-fragment layout per step ----------------
__global__ void k_prenet(const float* __restrict__ dec_in,
                         const float* __restrict__ W1, const float* __restrict__ b1,
                         const float* __restrict__ W2, const float* __restrict__ b2,
                         char* __restrict__ wsb) {
  int s = blockIdx.x, b = blockIdx.y, th = threadIdx.x;
  __shared__ float frame[80];
  __shared__ float h1[256];
  if (th < 80) frame[th] = (s == 0) ? 0.f : dec_in[(b * 80 + th) * 64 + (s - 1)];
  __syncthreads();
  float a = b1[th];
  const float* w1r = W1 + th * 80;
  for (int m = 0; m < 80; ++m) a += w1r[m] * frame[m];
  h1[th] = fmaxf(a, 0.f);
  __syncthreads();
  float a2 = b2[th];
  const float* w2r = W2 + th * 256;
  for (int i = 0; i < 256; ++i) a2 += w2r[i] * h1[i];
  float pre = fmaxf(a2, 0.f);
  int k = th;
  ((u16*)(wsb + OFF_PREF))[(((size_t)s * 8 + (k >> 5)) * 64 + ((k >> 3) & 3) * 16 + b) * 8 + (k & 7)] = f2bf(pre);
}

// ---------------- prep: processed_memory pm[b][tt][d] ----------------
__global__ void k_pm(const float* __restrict__ memory, char* __restrict__ wsb) {
  int bk = blockIdx.x, th = threadIdx.x;
  int b = bk >> 4, t0 = (bk & 15) * 16;
  __shared__ float mrow[16 * 512];
  for (int i = 0; i < 8; ++i) {
    int fi4 = i * 256 + th;
    int tl = fi4 >> 7, k4 = (fi4 & 127) << 2;
    *(float4*)&mrow[tl * 512 + k4] =
        *(const float4*)&memory[((size_t)(b * 256 + t0 + tl)) * 512 + k4];
  }
  __syncthreads();
  int d = th & 127, tl0 = th >> 7;
  float acc[8] = {};
  const float* mWT = (const float*)(wsb + OFF_MWT);
  float* pmw = (float*)(wsb + OFF_PM);
  for (int k = 0; k < 512; ++k) {
    float w = mWT[k * 128 + d];
#pragma unroll
    for (int i = 0; i < 8; ++i) acc[i] += w * mrow[(tl0 + i * 2) * 512 + k];
  }
  for (int i = 0; i < 8; ++i)
    pmw[((size_t)(b * 256 + t0 + tl0 + i * 2)) * 128 + d] = acc[i];
}

struct KParams {
  const float* memory;
  const int* mlen;
  const float* convW;
  const float* ldW;
  const float* attnv;
  const float* projW;
  const float* projb;
  const float* gateW;
  const float* gateb;
  char* wsb;
  float* out;
};

// attn "early" tiles for step t: PREF (pe<8) + AHFD (pe>=8) -> 10 MFMA per wave
__device__ __forceinline__ f32x4 attn_early(char* wsb, int t, int kc, int l,
                                            const short8* afE) {
  f32x4 acc = {0.f, 0.f, 0.f, 0.f};
#pragma unroll
  for (int i = 0; i < 10; ++i) {
    int pe = kc * 10 + i;
    const char* src = (pe < 8)
        ? wsb + OFF_PREF + (((size_t)t * 8 + pe) * 64 + l) * 16
        : wsb + OFF_AHFD + (((size_t)t * 32 + (pe - 8)) * 64 + l) * 16;
    short8 bv = ld_frag_nt(src);
    acc = __builtin_amdgcn_mfma_f32_16x16x32_bf16(afE[i], bv, acc, 0, 0, 0);
  }
  return acc;
}

// dec-LSTM step td = t-1 (reads AHFD[t], CTXFD[t], DHFD[t-1]; writes DHF[t], DHFD[t])
__device__ __forceinline__ void run_dec(char* wsb, int t, int tb, int th, int l, int w,
                                        int rt, int kc, float biasD_r, float& cD,
                                        float* smC) {
  const char* wfd = wsb + OFF_WFD;
  int tIdx = tb * 2 + rt;
  f32x4 acc = {0.f, 0.f, 0.f, 0.f};
#pragma unroll
  for (int i = 0; i < 20; ++i) {
    int kt = kc * 20 + i;
    short8 av = *(const short8*)(wfd + (((size_t)tIdx * 80 + kt) * 64 + l) * 16);
    const char* src;
    if (kt < 32)      src = wsb + OFF_AHFD + (((size_t)t * 32 + kt) * 64 + l) * 16;
    else if (kt < 48) src = wsb + OFF_CTXFD + (((size_t)t * 16 + (kt - 32)) * 64 + l) * 16;
    else              src = wsb + OFF_DHFD + (((size_t)(t - 1) * 32 + (kt - 48)) * 64 + l) * 16;
    short8 bv = ld_frag_nt(src);
    acc = __builtin_amdgcn_mfma_f32_16x16x32_bf16(av, bv, acc, 0, 0, 0);
  }
#pragma unroll
  for (int r4 = 0; r4 < 4; ++r4)
    smC[w * 256 + ((l >> 4) * 4 + r4) * 16 + (l & 15)] = acc[r4];
  __syncthreads();
  {
    int rt2 = th >> 8, r = (th >> 4) & 15, b2 = th & 15;
    float s = 0.f;
#pragma unroll
    for (int q = 0; q < 4; ++q) s += smC[(q * 2 + rt2) * 256 + r * 16 + b2];
    smC[4096 + th] = s + biasD_r;
  }
  __syncthreads();
  if (th < 128) {
    int b = th & 15, lu = th >> 4;
    int rt3 = lu >> 2, ul = lu & 3;
    int u = (tb * 2 + rt3) * 4 + ul;
    float gi = smC[4096 + rt3 * 256 + ul * 16 + b];
    float gf = smC[4096 + rt3 * 256 + (4 + ul) * 16 + b];
    float gc = smC[4096 + rt3 * 256 + (8 + ul) * 16 + b];
    float go = smC[4096 + rt3 * 256 + (12 + ul) * 16 + b];
    float c2 = sigmf(gf) * cD + sigmf(gi) * tanhf(gc);
    float h2 = sigmf(go) * tanhf(c2);
    cD = c2;
    st_f32_agent((float*)(wsb + OFF_DHF) + ((size_t)t * 1024 + u) * 16 + b, h2);
    st_u16_agent((u16*)(wsb + OFF_DHFD) +
                 ((((size_t)t * 32 + (u >> 5)) * 64 + ((u >> 3) & 3) * 16 + b) * 8 + (u & 7)),
                 f2bf(h2));
  }
}

// ---------------- main persistent kernel (dataflow, no barriers) ---------------
// Roles: bk 0..15: conv(t) + phase-B(t), publish B-flag.
//        bk 16..143: late-attn(t) on Bf(t); early-attn(t+1) + dec(t-1) in shadow.
//        bk 144..255: long-sleep idle; wait final flags; epilogue (all blocks).
__global__ void __launch_bounds__(512, 1) k_main(KParams p) {
  const int th = threadIdx.x;
  const int bk = blockIdx.x;
  char* wsb = p.wsb;
  const int l = th & 63, w = th >> 6;
  u32* Af = (u32*)(wsb + OFF_BAR);            // 128 packed
  u32* Df = (u32*)(wsb + OFF_BAR + 1024);     // 128 packed
  u32* Bf = (u32*)(wsb + OFF_BAR + 2048);     // 16 strided (x16 u32)

  __shared__ float smC[4608];
  __shared__ float s2q[128], s2v[128];
  __shared__ u16 s_convF[8192];               // conv bf16 A-frags: [16 tiles][64][8]
  __shared__ __align__(16) float s2ah[1024];
  __shared__ float s_e[256], s3wr[4];
  __shared__ float s1cw[1984];                // convW 32*62
  __shared__ float s_aw[256], s_awc[256];     // per-b attention state (blocks 0..15)

  const float* pm = (const float*)(wsb + OFF_PM);
  const u16* qwb = (const u16*)(wsb + OFF_QWB);

  if (bk < 16) {
    for (int i = th; i < 1984; i += 512) s1cw[i] = p.convW[i];
    for (int i = th; i < 4096; i += 512) ((u32*)s_convF)[i] = 0u;
    if (th < 128) s2v[th] = p.attnv[th];
    if (th < 256) { s_aw[th] = 0.f; s_awc[th] = 0.f; }
  }

  float biasA_r = 0.f, biasD_r = 0.f;
  if (bk >= 16 && bk < 144) {
    int r = (th >> 4) & 15, rt2 = th >> 8, tbase = (bk - 16) * 2;
    biasA_r = ((const float*)(wsb + OFF_BA))[(r >> 2) * 1024 + (tbase + rt2) * 4 + (r & 3)];
    biasD_r = ((const float*)(wsb + OFF_BD))[(r >> 2) * 1024 + (tbase + rt2) * 4 + (r & 3)];
  }
  int lenB = 0;
  if (bk < 16) lenB = p.mlen[bk];
  float cA = 0.f, cD = 0.f;

  const int rt = w & 1, kc = w >> 1;
  // attn A-frags, early/late split: early pool = {kt<8} U {kt>=24} (40 tiles),
  // late pool = {8<=kt<24} (16 CTXFD tiles); each wave: 10 early + 4 late.
  short8 afE[10], afL[4];
  if (bk >= 16 && bk < 144) {
    const char* wfa = wsb + OFF_WFA;
    int tIdx = (bk - 16) * 2 + rt;
#pragma unroll
    for (int i = 0; i < 10; ++i) {
      int pe = kc * 10 + i;
      int kt = (pe < 8) ? pe : (24 + (pe - 8));
      afE[i] = *(const short8*)(wfa + (((size_t)tIdx * 56 + kt) * 64 + l) * 16);
    }
#pragma unroll
    for (int i = 0; i < 4; ++i) {
      int kt = 8 + kc * 4 + i;
      afL[i] = *(const short8*)(wfa + (((size_t)tIdx * 56 + kt) * 64 + l) * 16);
    }
  }
  // ldw B-frags in registers (phase-B blocks)
  short8 ldwB[8];
  if (bk < 16) {
    int kg = l >> 4, dcol = l & 15;
#pragma unroll
    for (int dt = 0; dt < 8; ++dt) {
      short8 v;
#pragma unroll
      for (int e = 0; e < 8; ++e)
        v[e] = (short)f2bf(p.ldW[(dt * 16 + dcol) * 32 + kg * 8 + e]);
      ldwB[dt] = v;
    }
  }
  __syncthreads();

  if (bk >= 16 && bk < 144) {
    // ============== attn (early/late) + dec pipeline ==============
    const int tb = bk - 16;
    f32x4 acc = attn_early(wsb, 0, kc, l, afE);   // slot-0 inputs (zeroed/ready)
    for (int t = 0; t < 64; ++t) {
      wait_s16<4>(Bf, (u32)t, th);                // ctx(t-1) published
      // late tiles: 4 CTXFD MFMA
#pragma unroll
      for (int i = 0; i < 4; ++i) {
        int ct = kc * 4 + i;
        short8 bv = ld_frag_nt(wsb + OFF_CTXFD + (((size_t)t * 16 + ct) * 64 + l) * 16);
        acc = __builtin_amdgcn_mfma_f32_16x16x32_bf16(afL[i], bv, acc, 0, 0, 0);
      }
#pragma unroll
      for (int r4 = 0; r4 < 4; ++r4)
        smC[w * 256 + ((l >> 4) * 4 + r4) * 16 + (l & 15)] = acc[r4];
      __syncthreads();
      {
        int rt2 = th >> 8, r = (th >> 4) & 15, b2 = th & 15;
        float s = 0.f;
#pragma unroll
        for (int q = 0; q < 4; ++q) s += smC[(q * 2 + rt2) * 256 + r * 16 + b2];
        smC[4096 + th] = s + biasA_r;
      }
      __syncthreads();
      if (th < 128) {
        int b = th & 15, lu = th >> 4;
        int rt3 = lu >> 2, ul = lu & 3;
        int u = (tb * 2 + rt3) * 4 + ul;
        float gi = smC[4096 + rt3 * 256 + ul * 16 + b];
        float gf = smC[4096 + rt3 * 256 + (4 + ul) * 16 + b];
        float gc = smC[4096 + rt3 * 256 + (8 + ul) * 16 + b];
        float go = smC[4096 + rt3 * 256 + (12 + ul) * 16 + b];
        float c2 = sigmf(gf) * cA + sigmf(gi) * tanhf(gc);
        float h2 = sigmf(go) * tanhf(c2);
        cA = c2;
        st_u16_agent((u16*)(wsb + OFF_AHFD) +
                     ((((size_t)(t + 1) * 32 + (u >> 5)) * 64 + ((u >> 3) & 3) * 16 + b) * 8 + (u & 7)),
                     f2bf(h2));
      }
      __syncthreads();                            // drain frag stores
      if (th == 0) st_u32_agent(Af + tb, (u32)(t + 1));
      // shadow work: dec(t-1), then speculative early(t+1)
      if (t >= 1) {
        wait_p128<4>(Df, (u32)(t - 1), th);
        run_dec(wsb, t, tb, th, l, w, rt, kc, biasD_r, cD, smC);
        __syncthreads();
        if (th == 0) st_u32_agent(Df + tb, (u32)t);
      }
      if (t < 63) {
        wait_p128<4>(Af, (u32)(t + 1), th);       // ah(t) fully published
        acc = attn_early(wsb, t + 1, kc, l, afE);
      }
    }
    // tail: dec(63)
    wait_s16<4>(Bf, 64u, th);
    wait_p128<4>(Df, 63u, th);
    run_dec(wsb, 64, tb, th, l, w, rt, kc, biasD_r, cD, smC);
    __syncthreads();
    if (th == 0) st_u32_agent(Df + tb, 64u);
  } else if (bk < 16) {
    // ============== conv + phase-B pipeline ==============
    const int b = bk;
    for (int t = 0; t < 64; ++t) {
      {  // conv(t) from own-LDS aw/awc -> bf16 A-frag layout in s_convF
        int jmax = (lenB + 15) >> 4;
        for (int j = 0; j < jmax; ++j) {
          int idx = j * 512 + th, tt = idx >> 5, f = idx & 31;
          float a = 0.f;
          const float* w0 = s1cw + f * 62;
#pragma unroll
          for (int kk = 0; kk < 31; ++kk) {
            int pos = tt + kk - 15;
            bool ok = (pos >= 0 && pos < 256);
            float awv = ok ? s_aw[pos] : 0.f;
            float awcv = ok ? s_awc[pos] : 0.f;
            a += awv * w0[kk] + awcv * w0[31 + kk];
          }
          s_convF[(tt >> 4) * 512 + ((f >> 3) * 16 + (tt & 15)) * 8 + (f & 7)] = f2bf(a);
        }
      }
      wait_p128<4>(Af, (u32)(t + 1), th);       // ah(t) published (fences s_convF too)
      if (th < 128) {   // stage ah(t) from AHFD[t+1] (NT)
        int o = th;
        short8 v = ld_frag_nt(wsb + OFF_AHFD +
                    (((size_t)(t + 1) * 32 + (o >> 2)) * 64 + (o & 3) * 16 + b) * 16);
#pragma unroll
        for (int e = 0; e < 8; ++e) s2ah[o * 8 + e] = bf2f((u16)v[e]);
      }
      __syncthreads();
      {  // query partials
        int d = th & 127, part = th >> 7;
        const u16* qr = qwb + d * 1024 + part * 256;
        const float* ah = s2ah + part * 256;
        float qa = 0.f;
        for (int kk = 0; kk < 256; kk += 8) {
          short8 v = *(const short8*)(qr + kk);
#pragma unroll
          for (int e = 0; e < 8; ++e) qa += bf2f((u16)v[e]) * ah[kk + e];
        }
        smC[part * 128 + d] = qa;
      }
      __syncthreads();
      if (th < 128) s2q[th] = smC[th] + smC[128 + th] + smC[256 + th] + smC[384 + th];
      __syncthreads();
      {  // energies via MFMA: wave w owns tt-tiles {2w, 2w+1}
#pragma unroll
        for (int tl = 0; tl < 2; ++tl) {
          int ttile = w * 2 + tl;
          short8 afc = *(const short8*)&s_convF[ttile * 512 + l * 8];
          int dcol = l & 15;
          float e0 = 0.f, e1 = 0.f, e2 = 0.f, e3 = 0.f;
          const float* pmb = pm + ((size_t)(b * 256 + ttile * 16 + (l >> 4) * 4)) * 128 + dcol;
#pragma unroll
          for (int dt = 0; dt < 8; ++dt) {
            f32x4 S = {0.f, 0.f, 0.f, 0.f};
            S = __builtin_amdgcn_mfma_f32_16x16x32_bf16(afc, ldwB[dt], S, 0, 0, 0);
            int d = dt * 16 + dcol;
            float qd = s2q[d], vd = s2v[d];
            e0 += vd * tanh_fast(qd + pmb[dt * 16 + 0 * 128] + S[0]);
            e1 += vd * tanh_fast(qd + pmb[dt * 16 + 1 * 128] + S[1]);
            e2 += vd * tanh_fast(qd + pmb[dt * 16 + 2 * 128] + S[2]);
            e3 += vd * tanh_fast(qd + pmb[dt * 16 + 3 * 128] + S[3]);
          }
#pragma unroll
          for (int off = 8; off; off >>= 1) {
            e0 += __shfl_xor(e0, off);
            e1 += __shfl_xor(e1, off);
            e2 += __shfl_xor(e2, off);
            e3 += __shfl_xor(e3, off);
          }
          if ((l & 15) == 0) {
            int tb0 = ttile * 16 + (l >> 4) * 4;
            s_e[tb0]     = (tb0     < lenB) ? __expf(e0) : 0.f;
            s_e[tb0 + 1] = (tb0 + 1 < lenB) ? __expf(e1) : 0.f;
            s_e[tb0 + 2] = (tb0 + 2 < lenB) ? __expf(e2) : 0.f;
            s_e[tb0 + 3] = (tb0 + 3 < lenB) ? __expf(e3) : 0.f;
          }
        }
      }
      __syncthreads();
      if (th < 256) {
        float v0 = s_e[th];
#pragma unroll
        for (int off = 32; off; off >>= 1) v0 += __shfl_xor(v0, off);
        if ((th & 63) == 0) s3wr[th >> 6] = v0;
      }
      __syncthreads();
      float rden = 1.f / (s3wr[0] + s3wr[1] + s3wr[2] + s3wr[3]);
      if (th < 256) {
        float a = s_e[th] * rden;
        s_aw[th] = a;
        s_awc[th] += a;
        p.out[82944 + ((size_t)(b * 64 + t)) * 256 + th] = a;
      }
      __syncthreads();
      {  // context: plain loads of memory (read-only, L2-resident)
        int dq = th & 127, tg = th >> 7;
        int d0 = dq * 4;
        float a0 = 0.f, a1 = 0.f, a2 = 0.f, a3 = 0.f;
        const float* mb = p.memory + ((size_t)b * 256) * 512 + d0;
        for (int tt = tg; tt < lenB; tt += 4) {
          float4 mv = *(const float4*)(mb + (size_t)tt * 512);
          float aw = s_aw[tt];
          a0 += aw * mv.x; a1 += aw * mv.y; a2 += aw * mv.z; a3 += aw * mv.w;
        }
        smC[tg * 512 + d0]     = a0;
        smC[tg * 512 + d0 + 1] = a1;
        smC[tg * 512 + d0 + 2] = a2;
        smC[tg * 512 + d0 + 3] = a3;
      }
      __syncthreads();
      {
        int d = th;
        float ctxv = smC[d] + smC[512 + d] + smC[1024 + d] + smC[1536 + d];
        st_f32_agent((float*)(wsb + OFF_CTXF) + ((size_t)(t + 1) * 512 + d) * 16 + b, ctxv);
        st_u16_agent((u16*)(wsb + OFF_CTXFD) +
                     ((((size_t)(t + 1) * 16 + (d >> 5)) * 64 + ((d >> 3) & 3) * 16 + b) * 8 + (d & 7)),
                     f2bf(ctxv));
      }
      __syncthreads();                          // drain ctx stores
      if (th == 0) st_u32_agent(Bf + b * 16, (u32)(t + 1));
    }
  }

  // ================= final dataflow sync + epilogue =================
  if (bk >= 144) {
    wait_p128<96>(Df, 64u, th);                 // long-sleep idle polling
    wait_s16<96>(Bf, 64u, th);
  } else {
    wait_p128<8>(Df, 64u, th);
    wait_s16<8>(Bf, 64u, th);
  }
  {
    int t = bk & 63, pa = bk >> 6;
    const float* dh = (const float*)(wsb + OFF_DHF) + (size_t)(t + 1) * 16384;
    const float* cx = (const float*)(wsb + OFF_CTXF) + (size_t)(t + 1) * 8192;
    int lim = (pa == 3) ? 336 : 320;
    for (int idx = th; idx < lim; idx += 512) {
      if (idx < 320) {
        int mi = idx >> 4, b = idx & 15, m = pa * 20 + mi;
        const float* wr = p.projW + (size_t)m * 1536;
        float a0 = 0.f, a1 = 0.f;
#pragma unroll 8
        for (int k = 0; k < 1024; k += 2) { a0 += wr[k] * dh[k * 16 + b]; a1 += wr[k + 1] * dh[(k + 1) * 16 + b]; }
#pragma unroll 8
        for (int k = 0; k < 512; k += 2)  { a0 += wr[1024 + k] * cx[k * 16 + b]; a1 += wr[1025 + k] * cx[(k + 1) * 16 + b]; }
        p.out[((size_t)(b * 80 + m)) * 64 + t] = a0 + a1 + p.projb[m];
      } else {
        int b = idx - 320;
        float a0 = 0.f, a1 = 0.f;
#pragma unroll 8
        for (int k = 0; k < 1024; k += 2) { a0 += p.gateW[k] * dh[k * 16 + b]; a1 += p.gateW[k + 1] * dh[(k + 1) * 16 + b]; }
#pragma unroll 8
        for (int k = 0; k < 512; k += 2)  { a0 += p.gateW[1024 + k] * cx[k * 16 + b]; a1 += p.gateW[1025 + k] * cx[(k + 1) * 16 + b]; }
        p.out[81920 + b * 64 + t] = a0 + a1 + p.gateb[0];
      }
    }
  }
}

// ---------------- host launcher ----------------
extern "C" void kernel_launch(void* const* d_in, const int* in_sizes, int n_in,
                              void* d_out, int out_size, void* d_ws, size_t ws_size,
                              hipStream_t stream) {
  (void)in_sizes; (void)n_in; (void)out_size; (void)ws_size;
  const float* memory = (const float*)d_in[0];
  const float* dec_in = (const float*)d_in[1];
  const int*   mlen   = (const int*)d_in[2];
  const float* pW1    = (const float*)d_in[3];
  const float* pb1    = (const float*)d_in[4];
  const float* pW2    = (const float*)d_in[5];
  const float* pb2    = (const float*)d_in[6];
  const float* aWih   = (const float*)d_in[7];
  const float* aWhh   = (const float*)d_in[8];
  const float* abih   = (const float*)d_in[9];
  const float* abhh   = (const float*)d_in[10];
  const float* qW     = (const float*)d_in[11];
  const float* memW   = (const float*)d_in[12];
  const float* convW  = (const float*)d_in[13];
  const float* ldW    = (const float*)d_in[14];
  const float* attnv  = (const float*)d_in[15];
  const float* dWih   = (const float*)d_in[16];
  const float* dWhh   = (const float*)d_in[17];
  const float* dbih   = (const float*)d_in[18];
  const float* dbhh   = (const float*)d_in[19];
  const float* projW  = (const float*)d_in[20];
  const float* projb  = (const float*)d_in[21];
  const float* gateW  = (const float*)d_in[22];
  const float* gateb  = (const float*)d_in[23];
  char* wsb = (char*)d_ws;
  float* out = (float*)d_out;

  // zero slot-0 fragments (initial states) + flag words (replay-safe)
  hipMemsetAsync(wsb + OFF_AHFD, 0, 32768, stream);
  hipMemsetAsync(wsb + OFF_CTXFD, 0, 16384, stream);
  hipMemsetAsync(wsb + OFF_DHFD, 0, 32768, stream);
  hipMemsetAsync(wsb + OFF_BAR, 0, 4096, stream);

  hipLaunchKernelGGL(k_wfrag, dim3(3584), dim3(256), 0, stream, aWih, aWhh, wsb + OFF_WFA, 56, 768);
  hipLaunchKernelGGL(k_wfrag, dim3(5120), dim3(256), 0, stream, dWih, dWhh, wsb + OFF_WFD, 80, 1536);
  hipLaunchKernelGGL(k_smallprep, dim3(800), dim3(256), 0, stream, memW, abih, abhh, dbih, dbhh, qW, wsb);
  hipLaunchKernelGGL(k_prenet, dim3(64, 16), dim3(256), 0, stream, dec_in, pW1, pb1, pW2, pb2, wsb);
  hipLaunchKernelGGL(k_pm, dim3(256), dim3(256), 0, stream, memory, wsb);

  KParams p{memory, mlen, convW, ldW, attnv, projW, projb, gateW, gateb, wsb, out};
  void* args[] = { &p };
  hipLaunchCooperativeKernel((void*)k_main, dim3(256), dim3(512), args, 0, stream);
}

// Round 13
// 2782.723 us; speedup vs baseline: 1.8920x; 1.0154x over previous
//
#include <hip/hip_runtime.h>

typedef __attribute__((ext_vector_type(8))) short short8;
typedef __attribute__((ext_vector_type(4))) float f32x4;
typedef unsigned short u16;
typedef unsigned int u32;
typedef unsigned long long u64;

// Shapes: B=16, T_ENC=256, T_DEC=64, N_MEL=80, ENC=512, ARNN=DRNN=1024,
// PRENET=256, ATTN_DIM=128, LOC_F=32, LOC_K=31
// attn LSTM K = 1792 (56 tiles of 32); dec K = 2560 (80 tiles)
// MFMA 16x16x32 bf16; C/D: col=lane&15, row=(lane>>4)*4+reg  [HW-verified]
//
// Coherence: cross-block WRITES agent-scope (land in LLC). Cross-block READS
// are nontemporal loads of step-versioned addresses. Sync: per-producer flags
// AGGREGATED by 3 dedicated blocks into single-word Aall/Dall/Ball; every
// consumer polls ONE line with ONE lane (kills the r11 poll storm).

// ---------------- workspace byte offsets ----------------
static constexpr size_t OFF_WFA   = 0;                 // 14,680,064
static constexpr size_t OFF_WFD   = 14680064;          // +20,971,520 = 35,651,584
static constexpr size_t OFF_PREF  = 35651584;          // +524,288
static constexpr size_t OFF_QWF   = 36175872;          // +262,144  qW A-frags (256 tiles)
static constexpr size_t OFF_MWT   = 36438016;          // +262,144
static constexpr size_t OFF_BA    = 36700160;          // +16,384
static constexpr size_t OFF_BD    = 36716544;          // +16,384
static constexpr size_t OFF_PM    = 36732928;          // +2,097,152  pm[b][tt][d] f32
static constexpr size_t OFF_CTXF  = 38830080;          // +2,129,920  [t][b][d] f32
static constexpr size_t OFF_DHF   = 40960000;          // +4,259,840  [t][u][b] f32
static constexpr size_t OFF_AHFD  = 45219840;          // +2,129,920  65 x 32KB frag
static constexpr size_t OFF_CTXFD = 47349760;          // +1,064,960  65 x 16KB frag
static constexpr size_t OFF_DHFD  = 48414720;          // +2,129,920  65 x 32KB frag
static constexpr size_t OFF_BAR   = 50544640;          // flags
static constexpr size_t OFF_END   = 50548736;
// flag layout within OFF_BAR: Af 128 packed u32 @0; Df 128 packed @1024;
// Bf 16 strided(x16) @2048; Aall @3072; Dall @3136; Ball @3200.

__device__ __forceinline__ float sigmf(float x) { return 1.f / (1.f + expf(-x)); }
__device__ __forceinline__ float tanh_fast(float x) {
  float e2 = __expf(2.f * x);
  return 1.f - 2.f / (e2 + 1.f);
}
__device__ __forceinline__ u16 f2bf(float f) {
  u32 u = __float_as_uint(f);
  return (u16)((u + 0x7FFFu + ((u >> 16) & 1u)) >> 16);
}
__device__ __forceinline__ float bf2f(u16 x) { return __uint_as_float(((u32)x) << 16); }

// nontemporal coalesced fragment load (no cache allocation; served by LLC)
__device__ __forceinline__ short8 ld_frag_nt(const void* p) {
  const u64* q = (const u64*)p;
  u64 lo = __builtin_nontemporal_load(q);
  u64 hi = __builtin_nontemporal_load(q + 1);
  union { u64 q2[2]; short8 s; } u;
  u.q2[0] = lo; u.q2[1] = hi;
  return u.s;
}

// agent-scope helpers (UC path)
__device__ __forceinline__ void st_u16_agent(u16* p, u16 v) {
  __hip_atomic_store(p, v, __ATOMIC_RELAXED, __HIP_MEMORY_SCOPE_AGENT);
}
__device__ __forceinline__ void st_f32_agent(float* p, float v) {
  __hip_atomic_store(p, v, __ATOMIC_RELAXED, __HIP_MEMORY_SCOPE_AGENT);
}
__device__ __forceinline__ void st_u64_agent(u64* p, u64 v) {
  __hip_atomic_store(p, v, __ATOMIC_RELAXED, __HIP_MEMORY_SCOPE_AGENT);
}
__device__ __forceinline__ u32 ld_u32_agent(const u32* p) {
  return __hip_atomic_load(p, __ATOMIC_RELAXED, __HIP_MEMORY_SCOPE_AGENT);
}
__device__ __forceinline__ void st_u32_agent(u32* p, u32 v) {
  __hip_atomic_store(p, v, __ATOMIC_RELAXED, __HIP_MEMORY_SCOPE_AGENT);
}

// single-line, single-lane consumer wait (SLP must be compile-time const)
template <int SLP>
__device__ __forceinline__ void wait_one(const u32* f, u32 target, int th) {
  if (th == 0) {
    while (ld_u32_agent(f) < target) __builtin_amdgcn_s_sleep(SLP);
  }
  __syncthreads();
}

// ---------------- prep: LSTM weights -> bf16 A-fragment layout ----------------
__global__ void k_wfrag(const float* __restrict__ Wih, const float* __restrict__ Whh,
                        char* __restrict__ dst, int NT, int Kih) {
  int idx = blockIdx.x * 256 + threadIdx.x;   // (tile*NT + s)*64 + l
  int l = idx & 63;
  int st = idx >> 6;
  int s = st % NT, tile = st / NT;
  int r = l & 15, kg = l >> 4;
  int j = (r >> 2) * 1024 + tile * 4 + (r & 3);
  int k0 = s * 32 + kg * 8;
  const float* src = (k0 < Kih) ? (Wih + (size_t)j * Kih + k0)
                                : (Whh + (size_t)j * 1024 + (k0 - Kih));
  short8 v;
#pragma unroll
  for (int e = 0; e < 8; ++e) v[e] = (short)f2bf(src[e]);
  *(short8*)(dst + (size_t)idx * 16) = v;
}

// ---------------- prep: qW -> bf16 A-fragments (8 d-tiles x 32 k-tiles) -------
__global__ void k_qwfrag(const float* __restrict__ qW, char* __restrict__ dst) {
  int idx = blockIdx.x * 256 + threadIdx.x;   // tile*64 + l, 16384 total
  int l = idx & 63, tile = idx >> 6;
  int dt = tile >> 5, kt = tile & 31;
  int j = dt * 16 + (l & 15);
  int k0 = kt * 32 + (l >> 4) * 8;
  short8 v;
#pragma unroll
  for (int e = 0; e < 8; ++e) v[e] = (short)f2bf(qW[j * 1024 + k0 + e]);
  *(short8*)(dst + (size_t)idx * 16) = v;
}

// ---------------- prep: memW^T, combined biases ----------------
__global__ void k_smallprep(const float* __restrict__ memW,
                            const float* __restrict__ abih, const float* __restrict__ abhh,
                            const float* __restrict__ dbih, const float* __restrict__ dbhh,
                            char* __restrict__ wsb) {
  int idx = blockIdx.x * 256 + threadIdx.x;
  if (idx < 65536) {
    int k = idx >> 7, d = idx & 127;
    ((float*)(wsb + OFF_MWT))[idx] = memW[d * 512 + k];
  } else if (idx < 69632) {
    int j = idx - 65536;
    ((float*)(wsb + OFF_BA))[j] = abih[j] + abhh[j];
  } else if (idx < 73728) {
    int j = idx - 69632;
    ((float*)(wsb + OFF_BD))[j] = dbih[j] + dbhh[j];
  }
}

// ---------------- prep: prenet -> bf16 B-fragment layout per step ----------------
__global__ void k_prenet(const float* __restrict__ dec_in,
                         const float* __restrict__ W1, const float* __restrict__ b1,
                         const float* __restrict__ W2, const float* __restrict__ b2,
                         char* __restrict__ wsb) {
  int s = blockIdx.x, b = blockIdx.y, th = threadIdx.x;
  __shared__ float frame[80];
  __shared__ float h1[256];
  if (th < 80) frame[th] = (s == 0) ? 0.f : dec_in[(b * 80 + th) * 64 + (s - 1)];
  __syncthreads();
  float a = b1[th];
  const float* w1r = W1 + th * 80;
  for (int m = 0; m < 80; ++m) a += w1r[m] * frame[m];
  h1[th] = fmaxf(a, 0.f);
  __syncthreads();
  float a2 = b2[th];
  const float* w2r = W2 + th * 256;
  for (int i = 0; i < 256; ++i) a2 += w2r[i] * h1[i];
  float pre = fmaxf(a2, 0.f);
  int k = th;
  ((u16*)(wsb + OFF_PREF))[(((size_t)s * 8 + (k >> 5)) * 64 + ((k >> 3) & 3) * 16 + b) * 8 + (k & 7)] = f2bf(pre);
}

// ---------------- prep: processed_memory pm[b][tt][d] ----------------
__global__ void k_pm(const float* __restrict__ memory, char* __restrict__ wsb) {
  int bk = blockIdx.x, th = threadIdx.x;
  int b = bk >> 4, t0 = (bk & 15) * 16;
  __shared__ float mrow[16 * 512];
  for (int i = 0; i < 8; ++i) {
    int fi4 = i * 256 + th;
    int tl = fi4 >> 7, k4 = (fi4 & 127) << 2;
    *(float4*)&mrow[tl * 512 + k4] =
        *(const float4*)&memory[((size_t)(b * 256 + t0 + tl)) * 512 + k4];
  }
  __syncthreads();
  int d = th & 127, tl0 = th >> 7;
  float acc[8] = {};
  const float* mWT = (const float*)(wsb + OFF_MWT);
  float* pmw = (float*)(wsb + OFF_PM);
  for (int k = 0; k < 512; ++k) {
    float w = mWT[k * 128 + d];
#pragma unroll
    for (int i = 0; i < 8; ++i) acc[i] += w * mrow[(tl0 + i * 2) * 512 + k];
  }
  for (int i = 0; i < 8; ++i)
    pmw[((size_t)(b * 256 + t0 + tl0 + i * 2)) * 128 + d] = acc[i];
}

struct KParams {
  const float* memory;
  const int* mlen;
  const float* convW;
  const float* ldW;
  const float* attnv;
  const float* projW;
  const float* projb;
  const float* gateW;
  const float* gateb;
  char* wsb;
  float* out;
};

// attn "early" tiles for step t: PREF (pe<8) + AHFD (pe>=8) -> 10 MFMA per wave
__device__ __forceinline__ f32x4 attn_early(char* wsb, int t, int kc, int l,
                                            const short8* afE) {
  f32x4 acc = {0.f, 0.f, 0.f, 0.f};
#pragma unroll
  for (int i = 0; i < 10; ++i) {
    int pe = kc * 10 + i;
    const char* src = (pe < 8)
        ? wsb + OFF_PREF + (((size_t)t * 8 + pe) * 64 + l) * 16
        : wsb + OFF_AHFD + (((size_t)t * 32 + (pe - 8)) * 64 + l) * 16;
    short8 bv = ld_frag_nt(src);
    acc = __builtin_amdgcn_mfma_f32_16x16x32_bf16(afE[i], bv, acc, 0, 0, 0);
  }
  return acc;
}

// dec-LSTM step td = t-1 (reads AHFD[t], CTXFD[t], DHFD[t-1]; writes DHF[t], DHFD[t])
__device__ __forceinline__ void run_dec(char* wsb, int t, int tb, int th, int l, int w,
                                        int rt, int kc, float biasD_r, float& cD,
                                        float* smC) {
  const char* wfd = wsb + OFF_WFD;
  int tIdx = tb * 2 + rt;
  f32x4 acc = {0.f, 0.f, 0.f, 0.f};
#pragma unroll
  for (int i = 0; i < 20; ++i) {
    int kt = kc * 20 + i;
    short8 av = *(const short8*)(wfd + (((size_t)tIdx * 80 + kt) * 64 + l) * 16);
    const char* src;
    if (kt < 32)      src = wsb + OFF_AHFD + (((size_t)t * 32 + kt) * 64 + l) * 16;
    else if (kt < 48) src = wsb + OFF_CTXFD + (((size_t)t * 16 + (kt - 32)) * 64 + l) * 16;
    else              src = wsb + OFF_DHFD + (((size_t)(t - 1) * 32 + (kt - 48)) * 64 + l) * 16;
    short8 bv = ld_frag_nt(src);
    acc = __builtin_amdgcn_mfma_f32_16x16x32_bf16(av, bv, acc, 0, 0, 0);
  }
#pragma unroll
  for (int r4 = 0; r4 < 4; ++r4)
    smC[w * 256 + ((l >> 4) * 4 + r4) * 16 + (l & 15)] = acc[r4];
  __syncthreads();
  {
    int rt2 = th >> 8, r = (th >> 4) & 15, b2 = th & 15;
    float s = 0.f;
#pragma unroll
    for (int q = 0; q < 4; ++q) s += smC[(q * 2 + rt2) * 256 + r * 16 + b2];
    smC[4096 + th] = s + biasD_r;
  }
  __syncthreads();
  if (th < 128) {
    int b = th & 15, lu = th >> 4;
    int rt3 = lu >> 2, ul = lu & 3;
    int u = (tb * 2 + rt3) * 4 + ul;
    float gi = smC[4096 + rt3 * 256 + ul * 16 + b];
    float gf = smC[4096 + rt3 * 256 + (4 + ul) * 16 + b];
    float gc = smC[4096 + rt3 * 256 + (8 + ul) * 16 + b];
    float go = smC[4096 + rt3 * 256 + (12 + ul) * 16 + b];
    float c2 = sigmf(gf) * cD + sigmf(gi) * tanhf(gc);
    float h2 = sigmf(go) * tanhf(c2);
    cD = c2;
    st_f32_agent((float*)(wsb + OFF_DHF) + ((size_t)t * 1024 + u) * 16 + b, h2);
    st_u16_agent((u16*)(wsb + OFF_DHFD) +
                 ((((size_t)t * 32 + (u >> 5)) * 64 + ((u >> 3) & 3) * 16 + b) * 8 + (u & 7)),
                 f2bf(h2));
  }
}

// ---------------- main persistent kernel (dataflow + flag aggregation) ---------
// Roles: bk 0..15: conv(t) + phase-B(t), publish Bf.
//        bk 16..143: late-attn(t) on Ball; early-attn(t+1) + dec(t-1) in shadow.
//        bk 144/145/146: aggregators Af->Aall, Df->Dall, Bf->Ball.
//        bk 147..255: idle; epilogue (all blocks).
__global__ void __launch_bounds__(512, 1) k_main(KParams p) {
  const int th = threadIdx.x;
  const int bk = blockIdx.x;
  char* wsb = p.wsb;
  const int l = th & 63, w = th >> 6;
  u32* Af = (u32*)(wsb + OFF_BAR);            // 128 packed
  u32* Df = (u32*)(wsb + OFF_BAR + 1024);     // 128 packed
  u32* Bf = (u32*)(wsb + OFF_BAR + 2048);     // 16 strided (x16 u32)
  u32* Aall = (u32*)(wsb + OFF_BAR + 3072);
  u32* Dall = (u32*)(wsb + OFF_BAR + 3136);
  u32* Ball = (u32*)(wsb + OFF_BAR + 3200);

  __shared__ float smC[4608];
  __shared__ float s2q[128], s2v[128];
  __shared__ u16 s_convF[8192];               // conv bf16 A-frags: [16 tiles][64][8]
  __shared__ u16 s_pack[512];                 // publish pack buffer
  __shared__ float s_e[256], s3wr[4];
  __shared__ float s1cw[1984];                // convW 32*62
  __shared__ float s_aw[256], s_awc[256];     // per-b attention state (blocks 0..15)

  const float* pm = (const float*)(wsb + OFF_PM);

  if (bk < 16) {
    for (int i = th; i < 1984; i += 512) s1cw[i] = p.convW[i];
    for (int i = th; i < 4096; i += 512) ((u32*)s_convF)[i] = 0u;
    if (th < 128) s2v[th] = p.attnv[th];
    if (th < 256) { s_aw[th] = 0.f; s_awc[th] = 0.f; }
  }

  float biasA_r = 0.f, biasD_r = 0.f;
  if (bk >= 16 && bk < 144) {
    int r = (th >> 4) & 15, rt2 = th >> 8, tbase = (bk - 16) * 2;
    biasA_r = ((const float*)(wsb + OFF_BA))[(r >> 2) * 1024 + (tbase + rt2) * 4 + (r & 3)];
    biasD_r = ((const float*)(wsb + OFF_BD))[(r >> 2) * 1024 + (tbase + rt2) * 4 + (r & 3)];
  }
  int lenB = 0;
  if (bk < 16) lenB = p.mlen[bk];
  float cA = 0.f, cD = 0.f;

  const int rt = w & 1, kc = w >> 1;
  short8 afE[10], afL[4];
  if (bk >= 16 && bk < 144) {
    const char* wfa = wsb + OFF_WFA;
    int tIdx = (bk - 16) * 2 + rt;
#pragma unroll
    for (int i = 0; i < 10; ++i) {
      int pe = kc * 10 + i;
      int kt = (pe < 8) ? pe : (24 + (pe - 8));
      afE[i] = *(const short8*)(wfa + (((size_t)tIdx * 56 + kt) * 64 + l) * 16);
    }
#pragma unroll
    for (int i = 0; i < 4; ++i) {
      int kt = 8 + kc * 4 + i;
      afL[i] = *(const short8*)(wfa + (((size_t)tIdx * 56 + kt) * 64 + l) * 16);
    }
  }
  // ldw B-frags in registers (phase-B blocks)
  short8 ldwB[8];
  if (bk < 16) {
    int kg = l >> 4, dcol = l & 15;
#pragma unroll
    for (int dt = 0; dt < 8; ++dt) {
      short8 v;
#pragma unroll
      for (int e = 0; e < 8; ++e)
        v[e] = (short)f2bf(p.ldW[(dt * 16 + dcol) * 32 + kg * 8 + e]);
      ldwB[dt] = v;
    }
  }
  __syncthreads();

  if (bk >= 16 && bk < 144) {
    // ============== attn (early/late) + dec pipeline ==============
    const int tb = bk - 16;
    f32x4 acc = attn_early(wsb, 0, kc, l, afE);   // slot-0 inputs (zeroed/ready)
    for (int t = 0; t < 64; ++t) {
      wait_one<1>(Ball, (u32)t, th);              // ctx(t-1) published
#pragma unroll
      for (int i = 0; i < 4; ++i) {
        int ct = kc * 4 + i;
        short8 bv = ld_frag_nt(wsb + OFF_CTXFD + (((size_t)t * 16 + ct) * 64 + l) * 16);
        acc = __builtin_amdgcn_mfma_f32_16x16x32_bf16(afL[i], bv, acc, 0, 0, 0);
      }
#pragma unroll
      for (int r4 = 0; r4 < 4; ++r4)
        smC[w * 256 + ((l >> 4) * 4 + r4) * 16 + (l & 15)] = acc[r4];
      __syncthreads();
      {
        int rt2 = th >> 8, r = (th >> 4) & 15, b2 = th & 15;
        float s = 0.f;
#pragma unroll
        for (int q = 0; q < 4; ++q) s += smC[(q * 2 + rt2) * 256 + r * 16 + b2];
        smC[4096 + th] = s + biasA_r;
      }
      __syncthreads();
      if (th < 128) {
        int b = th & 15, lu = th >> 4;
        float gi = smC[4096 + (lu >> 2) * 256 + (lu & 3) * 16 + b];
        float gf = smC[4096 + (lu >> 2) * 256 + (4 + (lu & 3)) * 16 + b];
        float gc = smC[4096 + (lu >> 2) * 256 + (8 + (lu & 3)) * 16 + b];
        float go = smC[4096 + (lu >> 2) * 256 + (12 + (lu & 3)) * 16 + b];
        float c2 = sigmf(gf) * cA + sigmf(gi) * tanhf(gc);
        float h2 = sigmf(go) * tanhf(c2);
        cA = c2;
        s_pack[b * 8 + lu] = f2bf(h2);            // u = tb*8 + lu
      }
      __syncthreads();
      if (th < 16) {  // coalesced AHFD publish: 16 b x 16B contiguous (256B)
        const u64* src = (const u64*)s_pack + th * 2;
        u64* dst = (u64*)(wsb + OFF_AHFD + ((size_t)(t + 1) * 32 + (tb >> 2)) * 1024 +
                          ((size_t)(tb & 3) * 16 + th) * 16);
        st_u64_agent(dst, src[0]);
        st_u64_agent(dst + 1, src[1]);
      }
      __syncthreads();                            // drain
      if (th == 0) st_u32_agent(Af + tb, (u32)(t + 1));
      if (t >= 1) {
        wait_one<1>(Dall, (u32)(t - 1), th);
        run_dec(wsb, t, tb, th, l, w, rt, kc, biasD_r, cD, smC);
        __syncthreads();
        if (th == 0) st_u32_agent(Df + tb, (u32)t);
      }
      if (t < 63) {
        wait_one<1>(Aall, (u32)(t + 1), th);      // ah(t) fully published
        acc = attn_early(wsb, t + 1, kc, l, afE);
      }
    }
    // tail: dec(63)
    wait_one<1>(Ball, 64u, th);
    wait_one<1>(Dall, 63u, th);
    run_dec(wsb, 64, tb, th, l, w, rt, kc, biasD_r, cD, smC);
    __syncthreads();
    if (th == 0) st_u32_agent(Df + tb, 64u);
  } else if (bk < 16) {
    // ============== conv + phase-B pipeline ==============
    const int b = bk;
    for (int t = 0; t < 64; ++t) {
      {  // conv(t) from own-LDS aw/awc -> bf16 A-frag layout in s_convF
        int jmax = (lenB + 15) >> 4;
        for (int j = 0; j < jmax; ++j) {
          int idx = j * 512 + th, tt = idx >> 5, f = idx & 31;
          float a = 0.f;
          const float* w0 = s1cw + f * 62;
#pragma unroll
          for (int kk = 0; kk < 31; ++kk) {
            int pos = tt + kk - 15;
            bool ok = (pos >= 0 && pos < 256);
            float awv = ok ? s_aw[pos] : 0.f;
            float awcv = ok ? s_awc[pos] : 0.f;
            a += awv * w0[kk] + awcv * w0[31 + kk];
          }
          s_convF[(tt >> 4) * 512 + ((f >> 3) * 16 + (tt & 15)) * 8 + (f & 7)] = f2bf(a);
        }
      }
      wait_one<1>(Aall, (u32)(t + 1), th);        // ah(t) published
      {  // query via MFMA: wave w = d-tile; ah octets as broadcast B-frags
        f32x4 qacc = {0.f, 0.f, 0.f, 0.f};
        const char* qwf = wsb + OFF_QWF;
#pragma unroll 4
        for (int kt = 0; kt < 32; ++kt) {
          short8 av = *(const short8*)(qwf + (((size_t)w * 32 + kt) * 64 + l) * 16);
          short8 bv = ld_frag_nt(wsb + OFF_AHFD + ((size_t)(t + 1) * 32 + kt) * 1024 +
                                 ((size_t)(l >> 4) * 16 + b) * 16);
          qacc = __builtin_amdgcn_mfma_f32_16x16x32_bf16(av, bv, qacc, 0, 0, 0);
        }
        if ((l & 15) == 0) {
          int r0 = (l >> 4) * 4;
          s2q[w * 16 + r0]     = qacc[0];
          s2q[w * 16 + r0 + 1] = qacc[1];
          s2q[w * 16 + r0 + 2] = qacc[2];
          s2q[w * 16 + r0 + 3] = qacc[3];
        }
      }
      __syncthreads();
      {  // energies via MFMA: wave w owns tt-tiles {2w, 2w+1}
#pragma unroll
        for (int tl = 0; tl < 2; ++tl) {
          int ttile = w * 2 + tl;
          short8 afc = *(const short8*)&s_convF[ttile * 512 + l * 8];
          int dcol = l & 15;
          float e0 = 0.f, e1 = 0.f, e2 = 0.f, e3 = 0.f;
          const float* pmb = pm + ((size_t)(b * 256 + ttile * 16 + (l >> 4) * 4)) * 128 + dcol;
#pragma unroll
          for (int dt = 0; dt < 8; ++dt) {
            f32x4 S = {0.f, 0.f, 0.f, 0.f};
            S = __builtin_amdgcn_mfma_f32_16x16x32_bf16(afc, ldwB[dt], S, 0, 0, 0);
            int d = dt * 16 + dcol;
            float qd = s2q[d], vd = s2v[d];
            e0 += vd * tanh_fast(qd + pmb[dt * 16 + 0 * 128] + S[0]);
            e1 += vd * tanh_fast(qd + pmb[dt * 16 + 1 * 128] + S[1]);
            e2 += vd * tanh_fast(qd + pmb[dt * 16 + 2 * 128] + S[2]);
            e3 += vd * tanh_fast(qd + pmb[dt * 16 + 3 * 128] + S[3]);
          }
#pragma unroll
          for (int off = 8; off; off >>= 1) {
            e0 += __shfl_xor(e0, off);
            e1 += __shfl_xor(e1, off);
            e2 += __shfl_xor(e2, off);
            e3 += __shfl_xor(e3, off);
          }
          if ((l & 15) == 0) {
            int tb0 = ttile * 16 + (l >> 4) * 4;
            s_e[tb0]     = (tb0     < lenB) ? __expf(e0) : 0.f;
            s_e[tb0 + 1] = (tb0 + 1 < lenB) ? __expf(e1) : 0.f;
            s_e[tb0 + 2] = (tb0 + 2 < lenB) ? __expf(e2) : 0.f;
            s_e[tb0 + 3] = (tb0 + 3 < lenB) ? __expf(e3) : 0.f;
          }
        }
      }
      __syncthreads();
      if (th < 256) {
        float v0 = s_e[th];
#pragma unroll
        for (int off = 32; off; off >>= 1) v0 += __shfl_xor(v0, off);
        if ((th & 63) == 0) s3wr[th >> 6] = v0;
      }
      __syncthreads();
      float rden = 1.f / (s3wr[0] + s3wr[1] + s3wr[2] + s3wr[3]);
      if (th < 256) {
        float a = s_e[th] * rden;
        s_aw[th] = a;
        s_awc[th] += a;
        p.out[82944 + ((size_t)(b * 64 + t)) * 256 + th] = a;
      }
      __syncthreads();
      {  // context: plain loads of memory (read-only, L2-resident)
        int dq = th & 127, tg = th >> 7;
        int d0 = dq * 4;
        float a0 = 0.f, a1 = 0.f, a2 = 0.f, a3 = 0.f;
        const float* mb = p.memory + ((size_t)b * 256) * 512 + d0;
        for (int tt = tg; tt < lenB; tt += 4) {
          float4 mv = *(const float4*)(mb + (size_t)tt * 512);
          float aw = s_aw[tt];
          a0 += aw * mv.x; a1 += aw * mv.y; a2 += aw * mv.z; a3 += aw * mv.w;
        }
        smC[tg * 512 + d0]     = a0;
        smC[tg * 512 + d0 + 1] = a1;
        smC[tg * 512 + d0 + 2] = a2;
        smC[tg * 512 + d0 + 3] = a3;
      }
      __syncthreads();
      {
        int d = th;
        float ctxv = smC[d] + smC[512 + d] + smC[1024 + d] + smC[1536 + d];
        st_f32_agent((float*)(wsb + OFF_CTXF) + (size_t)(t + 1) * 8192 + b * 512 + d, ctxv);
        s_pack[d] = f2bf(ctxv);
      }
      __syncthreads();
      if (th < 64) {  // coalesced CTXFD publish: octet o = th
        u64 p0 = ((const u64*)s_pack)[th * 2];
        u64 p1 = ((const u64*)s_pack)[th * 2 + 1];
        u64* dst = (u64*)(wsb + OFF_CTXFD + ((size_t)(t + 1) * 16 + (th >> 2)) * 1024 +
                          ((size_t)(th & 3) * 16 + b) * 16);
        st_u64_agent(dst, p0);
        st_u64_agent(dst + 1, p1);
      }
      __syncthreads();                          // drain ctx stores
      if (th == 0) st_u32_agent(Bf + b * 16, (u32)(t + 1));
    }
  } else if (bk == 144) {
    // aggregator: Af (128 packed) -> Aall
    if (th < 64) {
      for (u32 tgt = 1; tgt <= 64; ++tgt) {
        for (;;) {
          u32 v0 = ld_u32_agent(Af + th);
          u32 v1 = ld_u32_agent(Af + 64 + th);
          u32 mn = v0 < v1 ? v0 : v1;
          if (__all(mn >= tgt)) break;
          __builtin_amdgcn_s_sleep(1);
        }
        if (th == 0) st_u32_agent(Aall, tgt);
      }
    }
    __syncthreads();
  } else if (bk == 145) {
    // aggregator: Df (128 packed) -> Dall
    if (th < 64) {
      for (u32 tgt = 1; tgt <= 64; ++tgt) {
        for (;;) {
          u32 v0 = ld_u32_agent(Df + th);
          u32 v1 = ld_u32_agent(Df + 64 + th);
          u32 mn = v0 < v1 ? v0 : v1;
          if (__all(mn >= tgt)) break;
          __builtin_amdgcn_s_sleep(1);
        }
        if (th == 0) st_u32_agent(Dall, tgt);
      }
    }
    __syncthreads();
  } else if (bk == 146) {
    // aggregator: Bf (16 strided) -> Ball
    if (th < 64) {
      for (u32 tgt = 1; tgt <= 64; ++tgt) {
        for (;;) {
          u32 v = ld_u32_agent(Bf + (th & 15) * 16);
          if (__all(v >= tgt)) break;
          __builtin_amdgcn_s_sleep(1);
        }
        if (th == 0) st_u32_agent(Ball, tgt);
      }
    }
    __syncthreads();
  }

  // ================= final dataflow sync + epilogue =================
  if (bk >= 147) {
    wait_one<64>(Dall, 64u, th);
    wait_one<64>(Ball, 64u, th);
  } else {
    wait_one<4>(Dall, 64u, th);
    wait_one<4>(Ball, 64u, th);
  }
  {
    int t = bk & 63, pa = bk >> 6;
    const float* dh = (const float*)(wsb + OFF_DHF) + (size_t)(t + 1) * 16384;
    const float* cxt = (const float*)(wsb + OFF_CTXF) + (size_t)(t + 1) * 8192;
    int lim = (pa == 3) ? 336 : 320;
    for (int idx = th; idx < lim; idx += 512) {
      if (idx < 320) {
        int mi = idx >> 4, b = idx & 15, m = pa * 20 + mi;
        const float* wr = p.projW + (size_t)m * 1536;
        const float* cxb = cxt + b * 512;
        float a0 = 0.f, a1 = 0.f;
#pragma unroll 8
        for (int k = 0; k < 1024; k += 2) { a0 += wr[k] * dh[k * 16 + b]; a1 += wr[k + 1] * dh[(k + 1) * 16 + b]; }
#pragma unroll 8
        for (int k = 0; k < 512; k += 2)  { a0 += wr[1024 + k] * cxb[k]; a1 += wr[1025 + k] * cxb[k + 1]; }
        p.out[((size_t)(b * 80 + m)) * 64 + t] = a0 + a1 + p.projb[m];
      } else {
        int b = idx - 320;
        const float* cxb = cxt + b * 512;
        float a0 = 0.f, a1 = 0.f;
#pragma unroll 8
        for (int k = 0; k < 1024; k += 2) { a0 += p.gateW[k] * dh[k * 16 + b]; a1 += p.gateW[k + 1] * dh[(k + 1) * 16 + b]; }
#pragma unroll 8
        for (int k = 0; k < 512; k += 2)  { a0 += p.gateW[1024 + k] * cxb[k]; a1 += p.gateW[1025 + k] * cxb[k + 1]; }
        p.out[81920 + b * 64 + t] = a0 + a1 + p.gateb[0];
      }
    }
  }
}

// ---------------- host launcher ----------------
extern "C" void kernel_launch(void* const* d_in, const int* in_sizes, int n_in,
                              void* d_out, int out_size, void* d_ws, size_t ws_size,
                              hipStream_t stream) {
  (void)in_sizes; (void)n_in; (void)out_size; (void)ws_size;
  const float* memory = (const float*)d_in[0];
  const float* dec_in = (const float*)d_in[1];
  const int*   mlen   = (const int*)d_in[2];
  const float* pW1    = (const float*)d_in[3];
  const float* pb1    = (const float*)d_in[4];
  const float* pW2    = (const float*)d_in[5];
  const float* pb2    = (const float*)d_in[6];
  const float* aWih   = (const float*)d_in[7];
  const float* aWhh   = (const float*)d_in[8];
  const float* abih   = (const float*)d_in[9];
  const float* abhh   = (const float*)d_in[10];
  const float* qW     = (const float*)d_in[11];
  const float* memW   = (const float*)d_in[12];
  const float* convW  = (const float*)d_in[13];
  const float* ldW    = (const float*)d_in[14];
  const float* attnv  = (const float*)d_in[15];
  const float* dWih   = (const float*)d_in[16];
  const float* dWhh   = (const float*)d_in[17];
  const float* dbih   = (const float*)d_in[18];
  const float* dbhh   = (const float*)d_in[19];
  const float* projW  = (const float*)d_in[20];
  const float* projb  = (const float*)d_in[21];
  const float* gateW  = (const float*)d_in[22];
  const float* gateb  = (const float*)d_in[23];
  char* wsb = (char*)d_ws;
  float* out = (float*)d_out;

  // zero slot-0 fragments (initial states) + flag words (replay-safe)
  hipMemsetAsync(wsb + OFF_AHFD, 0, 32768, stream);
  hipMemsetAsync(wsb + OFF_CTXFD, 0, 16384, stream);
  hipMemsetAsync(wsb + OFF_DHFD, 0, 32768, stream);
  hipMemsetAsync(wsb + OFF_BAR, 0, 4096, stream);

  hipLaunchKernelGGL(k_wfrag, dim3(3584), dim3(256), 0, stream, aWih, aWhh, wsb + OFF_WFA, 56, 768);
  hipLaunchKernelGGL(k_wfrag, dim3(5120), dim3(256), 0, stream, dWih, dWhh, wsb + OFF_WFD, 80, 1536);
  hipLaunchKernelGGL(k_qwfrag, dim3(64), dim3(256), 0, stream, qW, wsb + OFF_QWF);
  hipLaunchKernelGGL(k_smallprep, dim3(288), dim3(256), 0, stream, memW, abih, abhh, dbih, dbhh, wsb);
  hipLaunchKernelGGL(k_prenet, dim3(64, 16), dim3(256), 0, stream, dec_in, pW1, pb1, pW2, pb2, wsb);
  hipLaunchKernelGGL(k_pm, dim3(256), dim3(256), 0, stream, memory, wsb);

  KParams p{memory, mlen, convW, ldW, attnv, projW, projb, gateW, gateb, wsb, out};
  void* args[] = { &p };
  hipLaunchCooperativeKernel((void*)k_main, dim3(256), dim3(512), args, 0, stream);
}

// Round 14
// 2689.893 us; speedup vs baseline: 1.9573x; 1.0345x over previous
//
#include <hip/hip_runtime.h>

typedef __attribute__((ext_vector_type(8))) short short8;
typedef __attribute__((ext_vector_type(4))) float f32x4;
typedef unsigned short u16;
typedef unsigned int u32;
typedef unsigned long long u64;

// Shapes: B=16, T_ENC=256, T_DEC=64, N_MEL=80, ENC=512, ARNN=DRNN=1024,
// PRENET=256, ATTN_DIM=128, LOC_F=32, LOC_K=31
// attn LSTM K = 1792 (56 tiles of 32); dec K = 2560 (80 tiles)
// MFMA 16x16x32 bf16; C/D: col=lane&15, row=(lane>>4)*4+reg  [HW-verified]
//
// Coherence: cross-block WRITES agent-scope (land in LLC). Cross-block READS
// are PLAIN CACHED loads of step-versioned addresses (virgin lines: written
// once via agent store before any read, reads gated by flags -> no stale L1/L2
// line can exist; across replays stale == fresh by determinism). r13 used
// nontemporal loads here - those skip LLC allocation entirely, making every
// fragment read a DRAM RTT and re-fetching each broadcast ~128x (the 325 MB
// FETCH and the ~43us/step floor). Plain loads: first reader per XCD pays one
// LLC RTT, rest hit L2.

// ---------------- workspace byte offsets ----------------
static constexpr size_t OFF_WFA   = 0;                 // 14,680,064
static constexpr size_t OFF_WFD   = 14680064;          // +20,971,520 = 35,651,584
static constexpr size_t OFF_PREF  = 35651584;          // +524,288
static constexpr size_t OFF_QWF   = 36175872;          // +262,144  qW A-frags (256 tiles)
static constexpr size_t OFF_MWT   = 36438016;          // +262,144
static constexpr size_t OFF_BA    = 36700160;          // +16,384
static constexpr size_t OFF_BD    = 36716544;          // +16,384
static constexpr size_t OFF_PM    = 36732928;          // +2,097,152  pm[b][tt][d] f32
static constexpr size_t OFF_CTXF  = 38830080;          // +2,129,920  [t][b][d] f32
static constexpr size_t OFF_DHF   = 40960000;          // +4,259,840  [t][u][b] f32
static constexpr size_t OFF_AHFD  = 45219840;          // +2,129,920  65 x 32KB frag
static constexpr size_t OFF_CTXFD = 47349760;          // +1,064,960  65 x 16KB frag
static constexpr size_t OFF_DHFD  = 48414720;          // +2,129,920  65 x 32KB frag
static constexpr size_t OFF_BAR   = 50544640;          // flags
static constexpr size_t OFF_END   = 50548736;
// flag layout within OFF_BAR: Af 128 packed u32 @0; Df 128 packed @1024;
// Bf 16 strided(x16) @2048; Aall @3072; Dall @3136; Ball @3200.

__device__ __forceinline__ float sigmf(float x) { return 1.f / (1.f + expf(-x)); }
__device__ __forceinline__ float tanh_fast(float x) {
  float e2 = __expf(2.f * x);
  return 1.f - 2.f / (e2 + 1.f);
}
__device__ __forceinline__ u16 f2bf(float f) {
  u32 u = __float_as_uint(f);
  return (u16)((u + 0x7FFFu + ((u >> 16) & 1u)) >> 16);
}
__device__ __forceinline__ float bf2f(u16 x) { return __uint_as_float(((u32)x) << 16); }

// cross-block fragment read: plain cached load (see coherence note above)
__device__ __forceinline__ short8 ld_frag(const void* p) {
  return *(const short8*)p;
}

// agent-scope helpers (UC path)
__device__ __forceinline__ void st_u16_agent(u16* p, u16 v) {
  __hip_atomic_store(p, v, __ATOMIC_RELAXED, __HIP_MEMORY_SCOPE_AGENT);
}
__device__ __forceinline__ void st_f32_agent(float* p, float v) {
  __hip_atomic_store(p, v, __ATOMIC_RELAXED, __HIP_MEMORY_SCOPE_AGENT);
}
__device__ __forceinline__ void st_u64_agent(u64* p, u64 v) {
  __hip_atomic_store(p, v, __ATOMIC_RELAXED, __HIP_MEMORY_SCOPE_AGENT);
}
__device__ __forceinline__ u32 ld_u32_agent(const u32* p) {
  return __hip_atomic_load(p, __ATOMIC_RELAXED, __HIP_MEMORY_SCOPE_AGENT);
}
__device__ __forceinline__ void st_u32_agent(u32* p, u32 v) {
  __hip_atomic_store(p, v, __ATOMIC_RELAXED, __HIP_MEMORY_SCOPE_AGENT);
}

// single-line, single-lane consumer wait (SLP must be compile-time const)
template <int SLP>
__device__ __forceinline__ void wait_one(const u32* f, u32 target, int th) {
  if (th == 0) {
    while (ld_u32_agent(f) < target) __builtin_amdgcn_s_sleep(SLP);
  }
  __syncthreads();
}

// ---------------- prep: LSTM weights -> bf16 A-fragment layout ----------------
__global__ void k_wfrag(const float* __restrict__ Wih, const float* __restrict__ Whh,
                        char* __restrict__ dst, int NT, int Kih) {
  int idx = blockIdx.x * 256 + threadIdx.x;   // (tile*NT + s)*64 + l
  int l = idx & 63;
  int st = idx >> 6;
  int s = st % NT, tile = st / NT;
  int r = l & 15, kg = l >> 4;
  int j = (r >> 2) * 1024 + tile * 4 + (r & 3);
  int k0 = s * 32 + kg * 8;
  const float* src = (k0 < Kih) ? (Wih + (size_t)j * Kih + k0)
                                : (Whh + (size_t)j * 1024 + (k0 - Kih));
  short8 v;
#pragma unroll
  for (int e = 0; e < 8; ++e) v[e] = (short)f2bf(src[e]);
  *(short8*)(dst + (size_t)idx * 16) = v;
}

// ---------------- prep: qW -> bf16 A-fragments (8 d-tiles x 32 k-tiles) -------
__global__ void k_qwfrag(const float* __restrict__ qW, char* __restrict__ dst) {
  int idx = blockIdx.x * 256 + threadIdx.x;   // tile*64 + l, 16384 total
  int l = idx & 63, tile = idx >> 6;
  int dt = tile >> 5, kt = tile & 31;
  int j = dt * 16 + (l & 15);
  int k0 = kt * 32 + (l >> 4) * 8;
  short8 v;
#pragma unroll
  for (int e = 0; e < 8; ++e) v[e] = (short)f2bf(qW[j * 1024 + k0 + e]);
  *(short8*)(dst + (size_t)idx * 16) = v;
}

// ---------------- prep: memW^T, combined biases ----------------
__global__ void k_smallprep(const float* __restrict__ memW,
                            const float* __restrict__ abih, const float* __restrict__ abhh,
                            const float* __restrict__ dbih, const float* __restrict__ dbhh,
                            char* __restrict__ wsb) {
  int idx = blockIdx.x * 256 + threadIdx.x;
  if (idx < 65536) {
    int k = idx >> 7, d = idx & 127;
    ((float*)(wsb + OFF_MWT))[idx] = memW[d * 512 + k];
  } else if (idx < 69632) {
    int j = idx - 65536;
    ((float*)(wsb + OFF_BA))[j] = abih[j] + abhh[j];
  } else if (idx < 73728) {
    int j = idx - 69632;
    ((float*)(wsb + OFF_BD))[j] = dbih[j] + dbhh[j];
  }
}

// ---------------- prep: prenet -> bf16 B-fragment layout per step ----------------
__global__ void k_prenet(const float* __restrict__ dec_in,
                         const float* __restrict__ W1, const float* __restrict__ b1,
                         const float* __restrict__ W2, const float* __restrict__ b2,
                         char* __restrict__ wsb) {
  int s = blockIdx.x, b = blockIdx.y, th = threadIdx.x;
  __shared__ float frame[80];
  __shared__ float h1[256];
  if (th < 80) frame[th] = (s == 0) ? 0.f : dec_in[(b * 80 + th) * 64 + (s - 1)];
  __syncthreads();
  float a = b1[th];
  const float* w1r = W1 + th * 80;
  for (int m = 0; m < 80; ++m) a += w1r[m] * frame[m];
  h1[th] = fmaxf(a, 0.f);
  __syncthreads();
  float a2 = b2[th];
  const float* w2r = W2 + th * 256;
  for (int i = 0; i < 256; ++i) a2 += w2r[i] * h1[i];
  float pre = fmaxf(a2, 0.f);
  int k = th;
  ((u16*)(wsb + OFF_PREF))[(((size_t)s * 8 + (k >> 5)) * 64 + ((k >> 3) & 3) * 16 + b) * 8 + (k & 7)] = f2bf(pre);
}

// ---------------- prep: processed_memory pm[b][tt][d] ----------------
__global__ void k_pm(const float* __restrict__ memory, char* __restrict__ wsb) {
  int bk = blockIdx.x, th = threadIdx.x;
  int b = bk >> 4, t0 = (bk & 15) * 16;
  __shared__ float mrow[16 * 512];
  for (int i = 0; i < 8; ++i) {
    int fi4 = i * 256 + th;
    int tl = fi4 >> 7, k4 = (fi4 & 127) << 2;
    *(float4*)&mrow[tl * 512 + k4] =
        *(const float4*)&memory[((size_t)(b * 256 + t0 + tl)) * 512 + k4];
  }
  __syncthreads();
  int d = th & 127, tl0 = th >> 7;
  float acc[8] = {};
  const float* mWT = (const float*)(wsb + OFF_MWT);
  float* pmw = (float*)(wsb + OFF_PM);
  for (int k = 0; k < 512; ++k) {
    float w = mWT[k * 128 + d];
#pragma unroll
    for (int i = 0; i < 8; ++i) acc[i] += w * mrow[(tl0 + i * 2) * 512 + k];
  }
  for (int i = 0; i < 8; ++i)
    pmw[((size_t)(b * 256 + t0 + tl0 + i * 2)) * 128 + d] = acc[i];
}

struct KParams {
  const float* memory;
  const int* mlen;
  const float* convW;
  const float* ldW;
  const float* attnv;
  const float* projW;
  const float* projb;
  const float* gateW;
  const float* gateb;
  char* wsb;
  float* out;
};

// attn "early" tiles for step t: PREF (pe<8) + AHFD (pe>=8) -> 10 MFMA per wave
__device__ __forceinline__ f32x4 attn_early(char* wsb, int t, int kc, int l,
                                            const short8* afE) {
  f32x4 acc = {0.f, 0.f, 0.f, 0.f};
#pragma unroll
  for (int i = 0; i < 10; ++i) {
    int pe = kc * 10 + i;
    const char* src = (pe < 8)
        ? wsb + OFF_PREF + (((size_t)t * 8 + pe) * 64 + l) * 16
        : wsb + OFF_AHFD + (((size_t)t * 32 + (pe - 8)) * 64 + l) * 16;
    short8 bv = ld_frag(src);
    acc = __builtin_amdgcn_mfma_f32_16x16x32_bf16(afE[i], bv, acc, 0, 0, 0);
  }
  return acc;
}

// dec-LSTM step td = t-1 (reads AHFD[t], CTXFD[t], DHFD[t-1]; writes DHF[t], DHFD[t])
__device__ __forceinline__ void run_dec(char* wsb, int t, int tb, int th, int l, int w,
                                        int rt, int kc, float biasD_r, float& cD,
                                        float* smC) {
  const char* wfd = wsb + OFF_WFD;
  int tIdx = tb * 2 + rt;
  f32x4 acc = {0.f, 0.f, 0.f, 0.f};
#pragma unroll
  for (int i = 0; i < 20; ++i) {
    int kt = kc * 20 + i;
    short8 av = *(const short8*)(wfd + (((size_t)tIdx * 80 + kt) * 64 + l) * 16);
    const char* src;
    if (kt < 32)      src = wsb + OFF_AHFD + (((size_t)t * 32 + kt) * 64 + l) * 16;
    else if (kt < 48) src = wsb + OFF_CTXFD + (((size_t)t * 16 + (kt - 32)) * 64 + l) * 16;
    else              src = wsb + OFF_DHFD + (((size_t)(t - 1) * 32 + (kt - 48)) * 64 + l) * 16;
    short8 bv = ld_frag(src);
    acc = __builtin_amdgcn_mfma_f32_16x16x32_bf16(av, bv, acc, 0, 0, 0);
  }
#pragma unroll
  for (int r4 = 0; r4 < 4; ++r4)
    smC[w * 256 + ((l >> 4) * 4 + r4) * 16 + (l & 15)] = acc[r4];
  __syncthreads();
  {
    int rt2 = th >> 8, r = (th >> 4) & 15, b2 = th & 15;
    float s = 0.f;
#pragma unroll
    for (int q = 0; q < 4; ++q) s += smC[(q * 2 + rt2) * 256 + r * 16 + b2];
    smC[4096 + th] = s + biasD_r;
  }
  __syncthreads();
  if (th < 128) {
    int b = th & 15, lu = th >> 4;
    int rt3 = lu >> 2, ul = lu & 3;
    int u = (tb * 2 + rt3) * 4 + ul;
    float gi = smC[4096 + rt3 * 256 + ul * 16 + b];
    float gf = smC[4096 + rt3 * 256 + (4 + ul) * 16 + b];
    float gc = smC[4096 + rt3 * 256 + (8 + ul) * 16 + b];
    float go = smC[4096 + rt3 * 256 + (12 + ul) * 16 + b];
    float c2 = sigmf(gf) * cD + sigmf(gi) * tanhf(gc);
    float h2 = sigmf(go) * tanhf(c2);
    cD = c2;
    st_f32_agent((float*)(wsb + OFF_DHF) + ((size_t)t * 1024 + u) * 16 + b, h2);
    st_u16_agent((u16*)(wsb + OFF_DHFD) +
                 ((((size_t)t * 32 + (u >> 5)) * 64 + ((u >> 3) & 3) * 16 + b) * 8 + (u & 7)),
                 f2bf(h2));
  }
}

// ---------------- main persistent kernel (dataflow + flag aggregation) ---------
// Roles: bk 0..15: conv(t) + phase-B(t), publish Bf.
//        bk 16..143: late-attn(t) on Ball; early-attn(t+1) + dec(t-1) in shadow.
//        bk 144/145/146: aggregators Af->Aall, Df->Dall, Bf->Ball.
//        bk 147..255: idle; epilogue (all blocks).
__global__ void __launch_bounds__(512, 1) k_main(KParams p) {
  const int th = threadIdx.x;
  const int bk = blockIdx.x;
  char* wsb = p.wsb;
  const int l = th & 63, w = th >> 6;
  u32* Af = (u32*)(wsb + OFF_BAR);            // 128 packed
  u32* Df = (u32*)(wsb + OFF_BAR + 1024);     // 128 packed
  u32* Bf = (u32*)(wsb + OFF_BAR + 2048);     // 16 strided (x16 u32)
  u32* Aall = (u32*)(wsb + OFF_BAR + 3072);
  u32* Dall = (u32*)(wsb + OFF_BAR + 3136);
  u32* Ball = (u32*)(wsb + OFF_BAR + 3200);

  __shared__ float smC[4608];
  __shared__ float s2q[128], s2v[128];
  __shared__ u16 s_convF[8192];               // conv bf16 A-frags: [16 tiles][64][8]
  __shared__ u16 s_pack[512];                 // publish pack buffer
  __shared__ float s_e[256], s3wr[4];
  __shared__ float s1cw[1984];                // convW 32*62
  __shared__ float s_aw[256], s_awc[256];     // per-b attention state (blocks 0..15)

  const float* pm = (const float*)(wsb + OFF_PM);

  if (bk < 16) {
    for (int i = th; i < 1984; i += 512) s1cw[i] = p.convW[i];
    for (int i = th; i < 4096; i += 512) ((u32*)s_convF)[i] = 0u;
    if (th < 128) s2v[th] = p.attnv[th];
    if (th < 256) { s_aw[th] = 0.f; s_awc[th] = 0.f; }
  }

  float biasA_r = 0.f, biasD_r = 0.f;
  if (bk >= 16 && bk < 144) {
    int r = (th >> 4) & 15, rt2 = th >> 8, tbase = (bk - 16) * 2;
    biasA_r = ((const float*)(wsb + OFF_BA))[(r >> 2) * 1024 + (tbase + rt2) * 4 + (r & 3)];
    biasD_r = ((const float*)(wsb + OFF_BD))[(r >> 2) * 1024 + (tbase + rt2) * 4 + (r & 3)];
  }
  int lenB = 0;
  if (bk < 16) lenB = p.mlen[bk];
  float cA = 0.f, cD = 0.f;

  const int rt = w & 1, kc = w >> 1;
  short8 afE[10], afL[4];
  if (bk >= 16 && bk < 144) {
    const char* wfa = wsb + OFF_WFA;
    int tIdx = (bk - 16) * 2 + rt;
#pragma unroll
    for (int i = 0; i < 10; ++i) {
      int pe = kc * 10 + i;
      int kt = (pe < 8) ? pe : (24 + (pe - 8));
      afE[i] = *(const short8*)(wfa + (((size_t)tIdx * 56 + kt) * 64 + l) * 16);
    }
#pragma unroll
    for (int i = 0; i < 4; ++i) {
      int kt = 8 + kc * 4 + i;
      afL[i] = *(const short8*)(wfa + (((size_t)tIdx * 56 + kt) * 64 + l) * 16);
    }
  }
  // ldw B-frags in registers (phase-B blocks)
  short8 ldwB[8];
  if (bk < 16) {
    int kg = l >> 4, dcol = l & 15;
#pragma unroll
    for (int dt = 0; dt < 8; ++dt) {
      short8 v;
#pragma unroll
      for (int e = 0; e < 8; ++e)
        v[e] = (short)f2bf(p.ldW[(dt * 16 + dcol) * 32 + kg * 8 + e]);
      ldwB[dt] = v;
    }
  }
  __syncthreads();

  if (bk >= 16 && bk < 144) {
    // ============== attn (early/late) + dec pipeline ==============
    const int tb = bk - 16;
    f32x4 acc = attn_early(wsb, 0, kc, l, afE);   // slot-0 inputs (zeroed/ready)
    for (int t = 0; t < 64; ++t) {
      wait_one<1>(Ball, (u32)t, th);              // ctx(t-1) published
#pragma unroll
      for (int i = 0; i < 4; ++i) {
        int ct = kc * 4 + i;
        short8 bv = ld_frag(wsb + OFF_CTXFD + (((size_t)t * 16 + ct) * 64 + l) * 16);
        acc = __builtin_amdgcn_mfma_f32_16x16x32_bf16(afL[i], bv, acc, 0, 0, 0);
      }
#pragma unroll
      for (int r4 = 0; r4 < 4; ++r4)
        smC[w * 256 + ((l >> 4) * 4 + r4) * 16 + (l & 15)] = acc[r4];
      __syncthreads();
      {
        int rt2 = th >> 8, r = (th >> 4) & 15, b2 = th & 15;
        float s = 0.f;
#pragma unroll
        for (int q = 0; q < 4; ++q) s += smC[(q * 2 + rt2) * 256 + r * 16 + b2];
        smC[4096 + th] = s + biasA_r;
      }
      __syncthreads();
      if (th < 128) {
        int b = th & 15, lu = th >> 4;
        float gi = smC[4096 + (lu >> 2) * 256 + (lu & 3) * 16 + b];
        float gf = smC[4096 + (lu >> 2) * 256 + (4 + (lu & 3)) * 16 + b];
        float gc = smC[4096 + (lu >> 2) * 256 + (8 + (lu & 3)) * 16 + b];
        float go = smC[4096 + (lu >> 2) * 256 + (12 + (lu & 3)) * 16 + b];
        float c2 = sigmf(gf) * cA + sigmf(gi) * tanhf(gc);
        float h2 = sigmf(go) * tanhf(c2);
        cA = c2;
        s_pack[b * 8 + lu] = f2bf(h2);            // u = tb*8 + lu
      }
      __syncthreads();
      if (th < 16) {  // coalesced AHFD publish: 16 b x 16B contiguous (256B)
        const u64* src = (const u64*)s_pack + th * 2;
        u64* dst = (u64*)(wsb + OFF_AHFD + ((size_t)(t + 1) * 32 + (tb >> 2)) * 1024 +
                          ((size_t)(tb & 3) * 16 + th) * 16);
        st_u64_agent(dst, src[0]);
        st_u64_agent(dst + 1, src[1]);
      }
      __syncthreads();                            // drain
      if (th == 0) st_u32_agent(Af + tb, (u32)(t + 1));
      if (t >= 1) {
        wait_one<1>(Dall, (u32)(t - 1), th);
        run_dec(wsb, t, tb, th, l, w, rt, kc, biasD_r, cD, smC);
        __syncthreads();
        if (th == 0) st_u32_agent(Df + tb, (u32)t);
      }
      if (t < 63) {
        wait_one<1>(Aall, (u32)(t + 1), th);      // ah(t) fully published
        acc = attn_early(wsb, t + 1, kc, l, afE);
      }
    }
    // tail: dec(63)
    wait_one<1>(Ball, 64u, th);
    wait_one<1>(Dall, 63u, th);
    run_dec(wsb, 64, tb, th, l, w, rt, kc, biasD_r, cD, smC);
    __syncthreads();
    if (th == 0) st_u32_agent(Df + tb, 64u);
  } else if (bk < 16) {
    // ============== conv + phase-B pipeline ==============
    const int b = bk;
    for (int t = 0; t < 64; ++t) {
      {  // conv(t) from own-LDS aw/awc -> bf16 A-frag layout in s_convF
        int jmax = (lenB + 15) >> 4;
        for (int j = 0; j < jmax; ++j) {
          int idx = j * 512 + th, tt = idx >> 5, f = idx & 31;
          float a = 0.f;
          const float* w0 = s1cw + f * 62;
#pragma unroll
          for (int kk = 0; kk < 31; ++kk) {
            int pos = tt + kk - 15;
            bool ok = (pos >= 0 && pos < 256);
            float awv = ok ? s_aw[pos] : 0.f;
            float awcv = ok ? s_awc[pos] : 0.f;
            a += awv * w0[kk] + awcv * w0[31 + kk];
          }
          s_convF[(tt >> 4) * 512 + ((f >> 3) * 16 + (tt & 15)) * 8 + (f & 7)] = f2bf(a);
        }
      }
      wait_one<1>(Aall, (u32)(t + 1), th);        // ah(t) published
      {  // query via MFMA: wave w = d-tile; ah octets as broadcast B-frags
        f32x4 qacc = {0.f, 0.f, 0.f, 0.f};
        const char* qwf = wsb + OFF_QWF;
#pragma unroll 4
        for (int kt = 0; kt < 32; ++kt) {
          short8 av = *(const short8*)(qwf + (((size_t)w * 32 + kt) * 64 + l) * 16);
          short8 bv = ld_frag(wsb + OFF_AHFD + ((size_t)(t + 1) * 32 + kt) * 1024 +
                              ((size_t)(l >> 4) * 16 + b) * 16);
          qacc = __builtin_amdgcn_mfma_f32_16x16x32_bf16(av, bv, qacc, 0, 0, 0);
        }
        if ((l & 15) == 0) {
          int r0 = (l >> 4) * 4;
          s2q[w * 16 + r0]     = qacc[0];
          s2q[w * 16 + r0 + 1] = qacc[1];
          s2q[w * 16 + r0 + 2] = qacc[2];
          s2q[w * 16 + r0 + 3] = qacc[3];
        }
      }
      __syncthreads();
      {  // energies via MFMA: wave w owns tt-tiles {2w, 2w+1}
#pragma unroll
        for (int tl = 0; tl < 2; ++tl) {
          int ttile = w * 2 + tl;
          short8 afc = *(const short8*)&s_convF[ttile * 512 + l * 8];
          int dcol = l & 15;
          float e0 = 0.f, e1 = 0.f, e2 = 0.f, e3 = 0.f;
          const float* pmb = pm + ((size_t)(b * 256 + ttile * 16 + (l >> 4) * 4)) * 128 + dcol;
#pragma unroll
          for (int dt = 0; dt < 8; ++dt) {
            f32x4 S = {0.f, 0.f, 0.f, 0.f};
            S = __builtin_amdgcn_mfma_f32_16x16x32_bf16(afc, ldwB[dt], S, 0, 0, 0);
            int d = dt * 16 + dcol;
            float qd = s2q[d], vd = s2v[d];
            e0 += vd * tanh_fast(qd + pmb[dt * 16 + 0 * 128] + S[0]);
            e1 += vd * tanh_fast(qd + pmb[dt * 16 + 1 * 128] + S[1]);
            e2 += vd * tanh_fast(qd + pmb[dt * 16 + 2 * 128] + S[2]);
            e3 += vd * tanh_fast(qd + pmb[dt * 16 + 3 * 128] + S[3]);
          }
#pragma unroll
          for (int off = 8; off; off >>= 1) {
            e0 += __shfl_xor(e0, off);
            e1 += __shfl_xor(e1, off);
            e2 += __shfl_xor(e2, off);
            e3 += __shfl_xor(e3, off);
          }
          if ((l & 15) == 0) {
            int tb0 = ttile * 16 + (l >> 4) * 4;
            s_e[tb0]     = (tb0     < lenB) ? __expf(e0) : 0.f;
            s_e[tb0 + 1] = (tb0 + 1 < lenB) ? __expf(e1) : 0.f;
            s_e[tb0 + 2] = (tb0 + 2 < lenB) ? __expf(e2) : 0.f;
            s_e[tb0 + 3] = (tb0 + 3 < lenB) ? __expf(e3) : 0.f;
          }
        }
      }
      __syncthreads();
      if (th < 256) {
        float v0 = s_e[th];
#pragma unroll
        for (int off = 32; off; off >>= 1) v0 += __shfl_xor(v0, off);
        if ((th & 63) == 0) s3wr[th >> 6] = v0;
      }
      __syncthreads();
      float rden = 1.f / (s3wr[0] + s3wr[1] + s3wr[2] + s3wr[3]);
      if (th < 256) {
        float a = s_e[th] * rden;
        s_aw[th] = a;
        s_awc[th] += a;
        p.out[82944 + ((size_t)(b * 64 + t)) * 256 + th] = a;
      }
      __syncthreads();
      {  // context: plain loads of memory (read-only, L2-resident)
        int dq = th & 127, tg = th >> 7;
        int d0 = dq * 4;
        float a0 = 0.f, a1 = 0.f, a2 = 0.f, a3 = 0.f;
        const float* mb = p.memory + ((size_t)b * 256) * 512 + d0;
        for (int tt = tg; tt < lenB; tt += 4) {
          float4 mv = *(const float4*)(mb + (size_t)tt * 512);
          float aw = s_aw[tt];
          a0 += aw * mv.x; a1 += aw * mv.y; a2 += aw * mv.z; a3 += aw * mv.w;
        }
        smC[tg * 512 + d0]     = a0;
        smC[tg * 512 + d0 + 1] = a1;
        smC[tg * 512 + d0 + 2] = a2;
        smC[tg * 512 + d0 + 3] = a3;
      }
      __syncthreads();
      {
        int d = th;
        float ctxv = smC[d] + smC[512 + d] + smC[1024 + d] + smC[1536 + d];
        st_f32_agent((float*)(wsb + OFF_CTXF) + (size_t)(t + 1) * 8192 + b * 512 + d, ctxv);
        s_pack[d] = f2bf(ctxv);
      }
      __syncthreads();
      if (th < 64) {  // coalesced CTXFD publish: octet o = th
        u64 p0 = ((const u64*)s_pack)[th * 2];
        u64 p1 = ((const u64*)s_pack)[th * 2 + 1];
        u64* dst = (u64*)(wsb + OFF_CTXFD + ((size_t)(t + 1) * 16 + (th >> 2)) * 1024 +
                          ((size_t)(th & 3) * 16 + b) * 16);
        st_u64_agent(dst, p0);
        st_u64_agent(dst + 1, p1);
      }
      __syncthreads();                          // drain ctx stores
      if (th == 0) st_u32_agent(Bf + b * 16, (u32)(t + 1));
    }
  } else if (bk == 144) {
    // aggregator: Af (128 packed) -> Aall
    if (th < 64) {
      for (u32 tgt = 1; tgt <= 64; ++tgt) {
        for (;;) {
          u32 v0 = ld_u32_agent(Af + th);
          u32 v1 = ld_u32_agent(Af + 64 + th);
          u32 mn = v0 < v1 ? v0 : v1;
          if (__all(mn >= tgt)) break;
          __builtin_amdgcn_s_sleep(1);
        }
        if (th == 0) st_u32_agent(Aall, tgt);
      }
    }
    __syncthreads();
  } else if (bk == 145) {
    // aggregator: Df (128 packed) -> Dall
    if (th < 64) {
      for (u32 tgt = 1; tgt <= 64; ++tgt) {
        for (;;) {
          u32 v0 = ld_u32_agent(Df + th);
          u32 v1 = ld_u32_agent(Df + 64 + th);
          u32 mn = v0 < v1 ? v0 : v1;
          if (__all(mn >= tgt)) break;
          __builtin_amdgcn_s_sleep(1);
        }
        if (th == 0) st_u32_agent(Dall, tgt);
      }
    }
    __syncthreads();
  } else if (bk == 146) {
    // aggregator: Bf (16 strided) -> Ball
    if (th < 64) {
      for (u32 tgt = 1; tgt <= 64; ++tgt) {
        for (;;) {
          u32 v = ld_u32_agent(Bf + (th & 15) * 16);
          if (__all(v >= tgt)) break;
          __builtin_amdgcn_s_sleep(1);
        }
        if (th == 0) st_u32_agent(Ball, tgt);
      }
    }
    __syncthreads();
  }

  // ================= final dataflow sync + epilogue =================
  if (bk >= 147) {
    wait_one<64>(Dall, 64u, th);
    wait_one<64>(Ball, 64u, th);
  } else {
    wait_one<4>(Dall, 64u, th);
    wait_one<4>(Ball, 64u, th);
  }
  {
    int t = bk & 63, pa = bk >> 6;
    const float* dh = (const float*)(wsb + OFF_DHF) + (size_t)(t + 1) * 16384;
    const float* cxt = (const float*)(wsb + OFF_CTXF) + (size_t)(t + 1) * 8192;
    int lim = (pa == 3) ? 336 : 320;
    for (int idx = th; idx < lim; idx += 512) {
      if (idx < 320) {
        int mi = idx >> 4, b = idx & 15, m = pa * 20 + mi;
        const float* wr = p.projW + (size_t)m * 1536;
        const float* cxb = cxt + b * 512;
        float a0 = 0.f, a1 = 0.f;
#pragma unroll 8
        for (int k = 0; k < 1024; k += 2) { a0 += wr[k] * dh[k * 16 + b]; a1 += wr[k + 1] * dh[(k + 1) * 16 + b]; }
#pragma unroll 8
        for (int k = 0; k < 512; k += 2)  { a0 += wr[1024 + k] * cxb[k]; a1 += wr[1025 + k] * cxb[k + 1]; }
        p.out[((size_t)(b * 80 + m)) * 64 + t] = a0 + a1 + p.projb[m];
      } else {
        int b = idx - 320;
        const float* cxb = cxt + b * 512;
        float a0 = 0.f, a1 = 0.f;
#pragma unroll 8
        for (int k = 0; k < 1024; k += 2) { a0 += p.gateW[k] * dh[k * 16 + b]; a1 += p.gateW[k + 1] * dh[(k + 1) * 16 + b]; }
#pragma unroll 8
        for (int k = 0; k < 512; k += 2)  { a0 += p.gateW[1024 + k] * cxb[k]; a1 += p.gateW[1025 + k] * cxb[k + 1]; }
        p.out[81920 + b * 64 + t] = a0 + a1 + p.gateb[0];
      }
    }
  }
}

// ---------------- host launcher ----------------
extern "C" void kernel_launch(void* const* d_in, const int* in_sizes, int n_in,
                              void* d_out, int out_size, void* d_ws, size_t ws_size,
                              hipStream_t stream) {
  (void)in_sizes; (void)n_in; (void)out_size; (void)ws_size;
  const float* memory = (const float*)d_in[0];
  const float* dec_in = (const float*)d_in[1];
  const int*   mlen   = (const int*)d_in[2];
  const float* pW1    = (const float*)d_in[3];
  const float* pb1    = (const float*)d_in[4];
  const float* pW2    = (const float*)d_in[5];
  const float* pb2    = (const float*)d_in[6];
  const float* aWih   = (const float*)d_in[7];
  const float* aWhh   = (const float*)d_in[8];
  const float* abih   = (const float*)d_in[9];
  const float* abhh   = (const float*)d_in[10];
  const float* qW     = (const float*)d_in[11];
  const float* memW   = (const float*)d_in[12];
  const float* convW  = (const float*)d_in[13];
  const float* ldW    = (const float*)d_in[14];
  const float* attnv  = (const float*)d_in[15];
  const float* dWih   = (const float*)d_in[16];
  const float* dWhh   = (const float*)d_in[17];
  const float* dbih   = (const float*)d_in[18];
  const float* dbhh   = (const float*)d_in[19];
  const float* projW  = (const float*)d_in[20];
  const float* projb  = (const float*)d_in[21];
  const float* gateW  = (const float*)d_in[22];
  const float* gateb  = (const float*)d_in[23];
  char* wsb = (char*)d_ws;
  float* out = (float*)d_out;

  // zero slot-0 fragments (initial states) + flag words (replay-safe)
  hipMemsetAsync(wsb + OFF_AHFD, 0, 32768, stream);
  hipMemsetAsync(wsb + OFF_CTXFD, 0, 16384, stream);
  hipMemsetAsync(wsb + OFF_DHFD, 0, 32768, stream);
  hipMemsetAsync(wsb + OFF_BAR, 0, 4096, stream);

  hipLaunchKernelGGL(k_wfrag, dim3(3584), dim3(256), 0, stream, aWih, aWhh, wsb + OFF_WFA, 56, 768);
  hipLaunchKernelGGL(k_wfrag, dim3(5120), dim3(256), 0, stream, dWih, dWhh, wsb + OFF_WFD, 80, 1536);
  hipLaunchKernelGGL(k_qwfrag, dim3(64), dim3(256), 0, stream, qW, wsb + OFF_QWF);
  hipLaunchKernelGGL(k_smallprep, dim3(288), dim3(256), 0, stream, memW, abih, abhh, dbih, dbhh, wsb);
  hipLaunchKernelGGL(k_prenet, dim3(64, 16), dim3(256), 0, stream, dec_in, pW1, pb1, pW2, pb2, wsb);
  hipLaunchKernelGGL(k_pm, dim3(256), dim3(256), 0, stream, memory, wsb);

  KParams p{memory, mlen, convW, ldW, attnv, projW, projb, gateW, gateb, wsb, out};
  void* args[] = { &p };
  hipLaunchCooperativeKernel((void*)k_main, dim3(256), dim3(512), args, 0, stream);
}